// Round 12
// baseline (1317.303 us; speedup 1.0000x reference)
//
#include <hip/hip_runtime.h>
#include <hip/hip_bf16.h>
#include <stdint.h>

#define T_TOK 16384
#define D_DIM 1024
#define E_NUM 8
#define H_DIM 2752
#define NSLOT (T_TOK * 2)

typedef __bf16 bf16x8_t __attribute__((ext_vector_type(8)));
typedef float f32x4_t __attribute__((ext_vector_type(4)));

__device__ __forceinline__ uint16_t f2bf(float f) {
    union { float f; uint32_t u; } v; v.f = f;
    return (uint16_t)((v.u + 0x7FFFu + ((v.u >> 16) & 1u)) >> 16);  // RNE
}
__device__ __forceinline__ ushort4 f4_to_bf4(float4 v) {
    ushort4 r; r.x = f2bf(v.x); r.y = f2bf(v.y); r.z = f2bf(v.z); r.w = f2bf(v.w);
    return r;
}
// async global->LDS, 16B/lane; HW writes LDS at (wave-uniform base) + lane*16
__device__ __forceinline__ void gl_lds16(const uint16_t* g, uint16_t* l) {
    __builtin_amdgcn_global_load_lds((const __attribute__((address_space(1))) void*)g,
                                     (__attribute__((address_space(3))) void*)l,
                                     16, 0, 0);
}

// ---------------- router: fp64 logits, softmax top-2 + fused x->bf16 --------
__global__ __launch_bounds__(256) void router_kernel(
    const float* __restrict__ x, const float* __restrict__ gw,
    int* __restrict__ topk_i, float* __restrict__ topk_w,
    uint16_t* __restrict__ Xb) {
    int tid = threadIdx.x;
    int t = blockIdx.x * 4 + (tid >> 6);
    int lane = tid & 63;
    const float* xr = x + (size_t)t * D_DIM;
    double acc[E_NUM];
#pragma unroll
    for (int e = 0; e < E_NUM; ++e) acc[e] = 0.0;
    for (int k = lane; k < D_DIM; k += 64) {
        double xv = (double)xr[k];
#pragma unroll
        for (int e = 0; e < E_NUM; ++e) acc[e] += xv * (double)gw[e * D_DIM + k];
    }
    // fused cvtx: row is L1/L2-hot from the dot-product pass
    {
        const float4* x4 = (const float4*)xr;
        ushort4* b4 = (ushort4*)(Xb + (size_t)t * D_DIM);
#pragma unroll
        for (int j = 0; j < 4; ++j) b4[lane + j * 64] = f4_to_bf4(x4[lane + j * 64]);
    }
#pragma unroll
    for (int e = 0; e < E_NUM; ++e) {
        double v = acc[e];
        for (int off = 32; off > 0; off >>= 1) v += __shfl_down(v, off, 64);
        acc[e] = v;
    }
    if (lane == 0) {
        int i0 = 0; double m0 = acc[0];
#pragma unroll
        for (int e = 1; e < E_NUM; ++e) if (acc[e] > m0) { m0 = acc[e]; i0 = e; }
        int i1 = -1; double m1 = -1.0e300;
#pragma unroll
        for (int e = 0; e < E_NUM; ++e) if (e != i0 && acc[e] > m1) { m1 = acc[e]; i1 = e; }
        double e1 = exp(m1 - m0);
        double s = 1.0 + e1;
        topk_i[t * 2 + 0] = i0; topk_i[t * 2 + 1] = i1;
        topk_w[t * 2 + 0] = (float)(1.0 / s);
        topk_w[t * 2 + 1] = (float)(e1 / s);
    }
}

// ---------------- count: LDS-aggregated histogram (1024 global atomics) -----
__global__ __launch_bounds__(256) void count_kernel(
    const int* __restrict__ topk_i,
    int* __restrict__ counts_f, int* __restrict__ counts_s) {
    __shared__ int hf[E_NUM], hs[E_NUM];
    int tid = threadIdx.x;
    if (tid < E_NUM) { hf[tid] = 0; hs[tid] = 0; }
    __syncthreads();
    int t = blockIdx.x * 256 + tid;
    atomicAdd(&hf[topk_i[t * 2 + 0]], 1);
    atomicAdd(&hs[topk_i[t * 2 + 1]], 1);
    __syncthreads();
    if (tid < E_NUM) {
        if (hf[tid]) atomicAdd(&counts_f[tid], hf[tid]);
    } else if (tid < 2 * E_NUM) {
        int e = tid - E_NUM;
        if (hs[e]) atomicAdd(&counts_s[e], hs[e]);
    }
}

__global__ void prefix_kernel(const int* __restrict__ cf, const int* __restrict__ cs,
                              int* __restrict__ bases, int* __restrict__ splits,
                              int* __restrict__ cnts) {
    int s = 0;
    for (int e = 0; e < E_NUM; ++e) {
        bases[e] = s;
        splits[e] = s + cf[e];
        cnts[e] = cf[e] + cs[e];
        s += cnts[e];
    }
}

// ---------------- assign: block-aggregated ranks (1024 global atomics) ------
__global__ __launch_bounds__(256) void assign_kernel(
    const int* __restrict__ topk_i, const float* __restrict__ topk_w,
    const int* __restrict__ bases, const int* __restrict__ splits,
    int* __restrict__ fills_f, int* __restrict__ fills_s,
    int* __restrict__ slot_tok, float* __restrict__ slot_w) {
    __shared__ int hf[E_NUM], hs[E_NUM], bf[E_NUM], bs[E_NUM];
    int tid = threadIdx.x;
    if (tid < E_NUM) { hf[tid] = 0; hs[tid] = 0; }
    __syncthreads();
    int t = blockIdx.x * 256 + tid;
    int e0 = topk_i[t * 2 + 0], e1 = topk_i[t * 2 + 1];
    int r0 = atomicAdd(&hf[e0], 1);
    int r1 = atomicAdd(&hs[e1], 1);
    __syncthreads();
    if (tid < E_NUM) {
        bf[tid] = hf[tid] ? atomicAdd(&fills_f[tid], hf[tid]) : 0;
    } else if (tid < 2 * E_NUM) {
        int e = tid - E_NUM;
        bs[e] = hs[e] ? atomicAdd(&fills_s[e], hs[e]) : 0;
    }
    __syncthreads();
    int s0 = bases[e0] + bf[e0] + r0;
    int s1 = splits[e1] + bs[e1] + r1;
    slot_tok[s0] = t; slot_w[s0] = topk_w[t * 2 + 0];
    slot_tok[s1] = t; slot_w[s1] = topk_w[t * 2 + 1];
}

// ---------------- converts --------------------------------------------------
// convert 4 experts' w1+w3 in one launch (group g: experts g*4..g*4+3)
__global__ __launch_bounds__(256) void cvt13g_kernel(const float* __restrict__ w1,
                                                     const float* __restrict__ w3,
                                                     uint16_t* __restrict__ w1be,
                                                     uint16_t* __restrict__ w3be, int g) {
    size_t i = (size_t)blockIdx.x * 256 + threadIdx.x;
    size_t off = (size_t)g * 4 * H_DIM * D_DIM / 4;
    ((ushort4*)w1be)[i] = f4_to_bf4(((const float4*)w1)[off + i]);
    ((ushort4*)w3be)[i] = f4_to_bf4(((const float4*)w3)[off + i]);
}
__global__ __launch_bounds__(256) void cvt2_kernel(const float* __restrict__ w2,
                                                   uint16_t* __restrict__ w2b) {
    size_t i = (size_t)blockIdx.x * 256 + threadIdx.x;
    ((ushort4*)w2b)[i] = f4_to_bf4(((const float4*)w2)[i]);
}

// ============================================================================
// 256-row M-tile, BK=64, 512 threads (8 waves = 4m x 2n), single-buffer 48KB
// LDS, 2-phase loop. Rationale: BK=64 (r11, +13% on gemm2) showed the lever
// is barrier-event amortization; 256M halves barrier events AND B re-stream
// per output again, with per-thread acc unchanged (64 f32).
// 3-bit XOR chunk swizzle (128B rows): store via pre-swizzled global source
// src_chunk = (lane&7) ^ ((w*4 + lane>>4)&7)  [rows = 64g + 8w + (lane>>3);
// 64g contributes 0 to (row>>1)&7], read chunk = (kk*4+kq) ^ ((rA>>1)&7).
// ============================================================================

// ---------------- gemm1 (4 experts/launch): hidden = silu(Xe@w1^T)*(Xe@w3^T)
// Tile 256(M) x 64(N, dual B1/B3). Wave-tile 64M x 32N x 2 mats.
__global__ __launch_bounds__(512, 4) void gemm1_kernel(
    const uint16_t* __restrict__ Xb, const uint16_t* __restrict__ w1be,
    const uint16_t* __restrict__ w3be, const int* __restrict__ slot_tok,
    const int* __restrict__ cnts, const int* __restrict__ bases,
    uint16_t* __restrict__ hidden, int g) {
    int ez = blockIdx.z;
    int e = g * 4 + ez;
    int cnt = cnts[e];
    int m0 = blockIdx.y * 256;
    if (m0 >= cnt) return;
    int n0 = blockIdx.x * 64;
    int base = bases[e];
    const uint16_t* w1p = w1be + (size_t)ez * H_DIM * D_DIM;
    const uint16_t* w3p = w3be + (size_t)ez * H_DIM * D_DIM;

    __shared__ __align__(16) uint16_t As[256 * 64];   // 32 KB
    __shared__ __align__(16) uint16_t B1s[64 * 64];   // 8 KB
    __shared__ __align__(16) uint16_t B3s[64 * 64];   // 8 KB

    int tid = threadIdx.x;
    int w = tid >> 6, lane = tid & 63;
    int wm = w >> 1, wn = w & 1;         // wave m-quarter / n-half
    int rA = lane & 15, kq = lane >> 4;
    int srcc = (lane & 7) ^ ((w * 4 + (lane >> 4)) & 7);  // store-side chunk
    int xr = (rA >> 1) & 7;              // read-side xor

    const uint16_t *pA0, *pA1, *pA2, *pA3, *pB1, *pB3;
    {
        int sr = w * 8 + (lane >> 3);    // staging row within 64-row group
        int t0 = slot_tok[base + min(m0 + 0 * 64 + sr, cnt - 1)];
        int t1 = slot_tok[base + min(m0 + 1 * 64 + sr, cnt - 1)];
        int t2 = slot_tok[base + min(m0 + 2 * 64 + sr, cnt - 1)];
        int t3 = slot_tok[base + min(m0 + 3 * 64 + sr, cnt - 1)];
        pA0 = Xb + (size_t)t0 * D_DIM + srcc * 8;
        pA1 = Xb + (size_t)t1 * D_DIM + srcc * 8;
        pA2 = Xb + (size_t)t2 * D_DIM + srcc * 8;
        pA3 = Xb + (size_t)t3 * D_DIM + srcc * 8;
        pB1 = w1p + (size_t)(n0 + sr) * D_DIM + srcc * 8;
        pB3 = w3p + (size_t)(n0 + sr) * D_DIM + srcc * 8;
    }
    uint16_t* lA0 = &As[(0 * 64 + w * 8) * 64];
    uint16_t* lA1 = &As[(1 * 64 + w * 8) * 64];
    uint16_t* lA2 = &As[(2 * 64 + w * 8) * 64];
    uint16_t* lA3 = &As[(3 * 64 + w * 8) * 64];
    uint16_t* lB1 = &B1s[(w * 8) * 64];
    uint16_t* lB3 = &B3s[(w * 8) * 64];

    f32x4_t acc1[4][2], acc3[4][2];
#pragma unroll
    for (int mf = 0; mf < 4; ++mf)
#pragma unroll
        for (int nf = 0; nf < 2; ++nf) {
            acc1[mf][nf] = (f32x4_t){0.f, 0.f, 0.f, 0.f};
            acc3[mf][nf] = (f32x4_t){0.f, 0.f, 0.f, 0.f};
        }

    for (int k0 = 0; k0 < D_DIM; k0 += 64) {  // 16 K-iters
        __syncthreads();
        gl_lds16(pA0, lA0);
        gl_lds16(pA1, lA1);
        gl_lds16(pA2, lA2);
        gl_lds16(pA3, lA3);
        gl_lds16(pB1, lB1);
        gl_lds16(pB3, lB3);
        pA0 += 64; pA1 += 64; pA2 += 64; pA3 += 64; pB1 += 64; pB3 += 64;
        __syncthreads();

#pragma unroll
        for (int kk = 0; kk < 2; ++kk) {
            int ck = ((kk * 4 + kq) ^ xr) * 8;
            bf16x8_t a[4], b1[2], b3[2];
#pragma unroll
            for (int mf = 0; mf < 4; ++mf)
                a[mf] = *(const bf16x8_t*)&As[(wm * 64 + mf * 16 + rA) * 64 + ck];
#pragma unroll
            for (int nf = 0; nf < 2; ++nf) {
                b1[nf] = *(const bf16x8_t*)&B1s[(wn * 32 + nf * 16 + rA) * 64 + ck];
                b3[nf] = *(const bf16x8_t*)&B3s[(wn * 32 + nf * 16 + rA) * 64 + ck];
            }
#pragma unroll
            for (int mf = 0; mf < 4; ++mf)
#pragma unroll
                for (int nf = 0; nf < 2; ++nf) {
                    acc1[mf][nf] = __builtin_amdgcn_mfma_f32_16x16x32_bf16(a[mf], b1[nf], acc1[mf][nf], 0, 0, 0);
                    acc3[mf][nf] = __builtin_amdgcn_mfma_f32_16x16x32_bf16(a[mf], b3[nf], acc3[mf][nf], 0, 0, 0);
                }
        }
    }

#pragma unroll
    for (int mf = 0; mf < 4; ++mf)
#pragma unroll
        for (int nf = 0; nf < 2; ++nf)
#pragma unroll
            for (int i = 0; i < 4; ++i) {
                int mrow = m0 + wm * 64 + mf * 16 + kq * 4 + i;
                if (mrow < cnt) {
                    float gv = acc1[mf][nf][i];
                    float s = gv / (1.0f + __expf(-gv));
                    float h = s * acc3[mf][nf][i];
                    hidden[(size_t)(base + mrow) * H_DIM + n0 + wn * 32 + nf * 16 + rA] = f2bf(h);
                }
            }
}

// ---------------- gemm2 (FUSED): out[tok] += w_slot * (hidden @ w2^T) -------
// Tile 256(M) x 128(N=D). Wave-tile 64M x 64N. atomicAdd into pre-zeroed out
// (commutative, == 2-pass). Striped XCD decode (prefix-safe).
__global__ __launch_bounds__(512, 4) void gemm2_kernel(
    const uint16_t* __restrict__ hidden, const uint16_t* __restrict__ w2b,
    const int* __restrict__ cnts, const int* __restrict__ bases,
    const int* __restrict__ slot_tok, const float* __restrict__ slot_w,
    float* __restrict__ out) {
    int e = blockIdx.z;
    int cnt = cnts[e];
    // lin in [0,512): j = lin>>3 in [0,64); m_t = (j>>3)*8 + (lin&7) in [0,64)
    int lin = blockIdx.y * 8 + blockIdx.x;
    int c8 = lin & 7, j = lin >> 3;
    int m_t = (j >> 3) * 8 + c8;             // m_t % 8 == c8 (XCD stripe)
    int x_t = j & 7;
    int m0 = m_t * 256;
    if (m0 >= cnt) return;
    int base = bases[e];
    int d0 = x_t * 128;

    __shared__ __align__(16) uint16_t As[256 * 64];  // 32 KB
    __shared__ __align__(16) uint16_t Bs[128 * 64];  // 16 KB

    int tid = threadIdx.x;
    int w = tid >> 6, lane = tid & 63;
    int wm = w >> 1, wn = w & 1;
    int rA = lane & 15, kq = lane >> 4;
    int srcc = (lane & 7) ^ ((w * 4 + (lane >> 4)) & 7);
    int xr = (rA >> 1) & 7;

    const uint16_t *pA0, *pA1, *pA2, *pA3, *pB0, *pB1;
    {
        int sr = w * 8 + (lane >> 3);
        int s0 = base + min(m0 + 0 * 64 + sr, cnt - 1);
        int s1 = base + min(m0 + 1 * 64 + sr, cnt - 1);
        int s2 = base + min(m0 + 2 * 64 + sr, cnt - 1);
        int s3 = base + min(m0 + 3 * 64 + sr, cnt - 1);
        pA0 = hidden + (size_t)s0 * H_DIM + srcc * 8;
        pA1 = hidden + (size_t)s1 * H_DIM + srcc * 8;
        pA2 = hidden + (size_t)s2 * H_DIM + srcc * 8;
        pA3 = hidden + (size_t)s3 * H_DIM + srcc * 8;
        pB0 = w2b + (size_t)(e * D_DIM + d0 + 0 * 64 + sr) * H_DIM + srcc * 8;
        pB1 = w2b + (size_t)(e * D_DIM + d0 + 1 * 64 + sr) * H_DIM + srcc * 8;
    }
    uint16_t* lA0 = &As[(0 * 64 + w * 8) * 64];
    uint16_t* lA1 = &As[(1 * 64 + w * 8) * 64];
    uint16_t* lA2 = &As[(2 * 64 + w * 8) * 64];
    uint16_t* lA3 = &As[(3 * 64 + w * 8) * 64];
    uint16_t* lB0 = &Bs[(0 * 64 + w * 8) * 64];
    uint16_t* lB1 = &Bs[(1 * 64 + w * 8) * 64];

    f32x4_t acc[4][4];
#pragma unroll
    for (int mf = 0; mf < 4; ++mf)
#pragma unroll
        for (int nf = 0; nf < 4; ++nf) acc[mf][nf] = (f32x4_t){0.f, 0.f, 0.f, 0.f};

    for (int k0 = 0; k0 < H_DIM; k0 += 64) {  // 43 K-iters
        __syncthreads();
        gl_lds16(pA0, lA0);
        gl_lds16(pA1, lA1);
        gl_lds16(pA2, lA2);
        gl_lds16(pA3, lA3);
        gl_lds16(pB0, lB0);
        gl_lds16(pB1, lB1);
        pA0 += 64; pA1 += 64; pA2 += 64; pA3 += 64; pB0 += 64; pB1 += 64;
        __syncthreads();

#pragma unroll
        for (int kk = 0; kk < 2; ++kk) {
            int ck = ((kk * 4 + kq) ^ xr) * 8;
            bf16x8_t a[4], b[4];
#pragma unroll
            for (int mf = 0; mf < 4; ++mf)
                a[mf] = *(const bf16x8_t*)&As[(wm * 64 + mf * 16 + rA) * 64 + ck];
#pragma unroll
            for (int nf = 0; nf < 4; ++nf)
                b[nf] = *(const bf16x8_t*)&Bs[(wn * 64 + nf * 16 + rA) * 64 + ck];
#pragma unroll
            for (int mf = 0; mf < 4; ++mf)
#pragma unroll
                for (int nf = 0; nf < 4; ++nf)
                    acc[mf][nf] = __builtin_amdgcn_mfma_f32_16x16x32_bf16(a[mf], b[nf], acc[mf][nf], 0, 0, 0);
        }
    }

#pragma unroll
    for (int mf = 0; mf < 4; ++mf)
#pragma unroll
        for (int i = 0; i < 4; ++i) {
            int mr = m0 + wm * 64 + mf * 16 + kq * 4 + i;
            if (mr < cnt) {
                int slot = base + mr;
                float wgt = slot_w[slot];
                int tok = slot_tok[slot];
                float* yr = out + (size_t)tok * D_DIM + d0 + wn * 64;
#pragma unroll
                for (int nf = 0; nf < 4; ++nf)
                    atomicAdd(&yr[nf * 16 + rA], wgt * acc[mf][nf][i]);
            }
        }
}

// ---------------- launch ----------------------------------------------------
extern "C" void kernel_launch(void* const* d_in, const int* in_sizes, int n_in,
                              void* d_out, int out_size, void* d_ws, size_t ws_size,
                              hipStream_t stream) {
    const float* x  = (const float*)d_in[0];
    const float* gw = (const float*)d_in[1];
    const float* w1 = (const float*)d_in[2];
    const float* w2 = (const float*)d_in[3];
    const float* w3 = (const float*)d_in[4];
    float* out = (float*)d_out;
    char* ws = (char*)d_ws;

    int*   counts_f = (int*)(ws + 0);
    int*   counts_s = (int*)(ws + 256);
    int*   fills_f  = (int*)(ws + 512);
    int*   fills_s  = (int*)(ws + 768);
    int*   bases    = (int*)(ws + 1024);
    int*   splits   = (int*)(ws + 1280);
    int*   cnts     = (int*)(ws + 1536);
    int*   topk_i   = (int*)(ws + 4096);
    float* topk_w   = (float*)(ws + 4096 + 1 * 131072);
    int*   slot_tok = (int*)(ws + 4096 + 2 * 131072);
    float* slot_w   = (float*)(ws + 4096 + 3 * 131072);

    // r5 layout: hidden @4MiB (180.36MB); W region 45.09MB after hidden
    // (gemm1: w1be+w3be group; gemm2: w2b). Xb in d_out (dead until gemm2).
    const size_t HID_OFF = 4ull << 20;
    const size_t W_OFF   = HID_OFF + (size_t)NSLOT * H_DIM * 2;
    const size_t W1SZ    = (size_t)H_DIM * D_DIM * 2;
    uint16_t* hidden = (uint16_t*)(ws + HID_OFF);
    uint16_t* w1be   = (uint16_t*)(ws + W_OFF);
    uint16_t* w3be   = (uint16_t*)(ws + W_OFF + 4 * W1SZ);
    uint16_t* w2b    = (uint16_t*)(ws + W_OFF);
    uint16_t* Xb     = (uint16_t*)d_out;

    hipMemsetAsync(ws, 0, 1024, stream);

    router_kernel<<<T_TOK / 4, 256, 0, stream>>>(x, gw, topk_i, topk_w, Xb);
    count_kernel<<<T_TOK / 256, 256, 0, stream>>>(topk_i, counts_f, counts_s);
    prefix_kernel<<<1, 1, 0, stream>>>(counts_f, counts_s, bases, splits, cnts);
    assign_kernel<<<T_TOK / 256, 256, 0, stream>>>(topk_i, topk_w, bases, splits,
                                                   fills_f, fills_s, slot_tok, slot_w);

    for (int g = 0; g < 2; ++g) {
        cvt13g_kernel<<<H_DIM * 4, 256, 0, stream>>>(w1, w3, w1be, w3be, g);
        // m padded to max cnt/256 = 64 tiles; dead tiles early-exit
        gemm1_kernel<<<dim3(H_DIM / 64, 64, 4), 512, 0, stream>>>(
            Xb, w1be, w3be, slot_tok, cnts, bases, hidden, g);
    }

    // Xb dead; zero out for atomic accumulation in fused gemm2.
    hipMemsetAsync(out, 0, (size_t)T_TOK * D_DIM * sizeof(float), stream);
    cvt2_kernel<<<E_NUM * D_DIM * H_DIM / 1024, 256, 0, stream>>>(w2, w2b);
    // 512 lin-blocks/expert: 64 m-tiles (striped) x 8 d-tiles
    gemm2_kernel<<<dim3(8, 64, E_NUM), 512, 0, stream>>>(
        hidden, w2b, cnts, bases, slot_tok, slot_w, out);
}

// Round 13
// 1211.026 us; speedup vs baseline: 1.0878x; 1.0878x over previous
//
#include <hip/hip_runtime.h>
#include <hip/hip_bf16.h>
#include <stdint.h>

#define T_TOK 16384
#define D_DIM 1024
#define E_NUM 8
#define H_DIM 2752
#define NSLOT (T_TOK * 2)

typedef __bf16 bf16x8_t __attribute__((ext_vector_type(8)));
typedef float f32x4_t __attribute__((ext_vector_type(4)));

__device__ __forceinline__ uint16_t f2bf(float f) {
    union { float f; uint32_t u; } v; v.f = f;
    return (uint16_t)((v.u + 0x7FFFu + ((v.u >> 16) & 1u)) >> 16);  // RNE
}
__device__ __forceinline__ ushort4 f4_to_bf4(float4 v) {
    ushort4 r; r.x = f2bf(v.x); r.y = f2bf(v.y); r.z = f2bf(v.z); r.w = f2bf(v.w);
    return r;
}
// async global->LDS, 16B/lane; HW writes LDS at (wave-uniform base) + lane*16
__device__ __forceinline__ void gl_lds16(const uint16_t* g, uint16_t* l) {
    __builtin_amdgcn_global_load_lds((const __attribute__((address_space(1))) void*)g,
                                     (__attribute__((address_space(3))) void*)l,
                                     16, 0, 0);
}

// ---------------- router: fp64 logits, softmax top-2 + fused x->bf16 --------
__global__ __launch_bounds__(256) void router_kernel(
    const float* __restrict__ x, const float* __restrict__ gw,
    int* __restrict__ topk_i, float* __restrict__ topk_w,
    uint16_t* __restrict__ Xb) {
    int tid = threadIdx.x;
    int t = blockIdx.x * 4 + (tid >> 6);
    int lane = tid & 63;
    const float* xr = x + (size_t)t * D_DIM;
    double acc[E_NUM];
#pragma unroll
    for (int e = 0; e < E_NUM; ++e) acc[e] = 0.0;
    for (int k = lane; k < D_DIM; k += 64) {
        double xv = (double)xr[k];
#pragma unroll
        for (int e = 0; e < E_NUM; ++e) acc[e] += xv * (double)gw[e * D_DIM + k];
    }
    // fused cvtx: row is L1/L2-hot from the dot-product pass
    {
        const float4* x4 = (const float4*)xr;
        ushort4* b4 = (ushort4*)(Xb + (size_t)t * D_DIM);
#pragma unroll
        for (int j = 0; j < 4; ++j) b4[lane + j * 64] = f4_to_bf4(x4[lane + j * 64]);
    }
#pragma unroll
    for (int e = 0; e < E_NUM; ++e) {
        double v = acc[e];
        for (int off = 32; off > 0; off >>= 1) v += __shfl_down(v, off, 64);
        acc[e] = v;
    }
    if (lane == 0) {
        int i0 = 0; double m0 = acc[0];
#pragma unroll
        for (int e = 1; e < E_NUM; ++e) if (acc[e] > m0) { m0 = acc[e]; i0 = e; }
        int i1 = -1; double m1 = -1.0e300;
#pragma unroll
        for (int e = 0; e < E_NUM; ++e) if (e != i0 && acc[e] > m1) { m1 = acc[e]; i1 = e; }
        double e1 = exp(m1 - m0);
        double s = 1.0 + e1;
        topk_i[t * 2 + 0] = i0; topk_i[t * 2 + 1] = i1;
        topk_w[t * 2 + 0] = (float)(1.0 / s);
        topk_w[t * 2 + 1] = (float)(e1 / s);
    }
}

// ---------------- count: LDS-aggregated histogram (1024 global atomics) -----
__global__ __launch_bounds__(256) void count_kernel(
    const int* __restrict__ topk_i,
    int* __restrict__ counts_f, int* __restrict__ counts_s) {
    __shared__ int hf[E_NUM], hs[E_NUM];
    int tid = threadIdx.x;
    if (tid < E_NUM) { hf[tid] = 0; hs[tid] = 0; }
    __syncthreads();
    int t = blockIdx.x * 256 + tid;
    atomicAdd(&hf[topk_i[t * 2 + 0]], 1);
    atomicAdd(&hs[topk_i[t * 2 + 1]], 1);
    __syncthreads();
    if (tid < E_NUM) {
        if (hf[tid]) atomicAdd(&counts_f[tid], hf[tid]);
    } else if (tid < 2 * E_NUM) {
        int e = tid - E_NUM;
        if (hs[e]) atomicAdd(&counts_s[e], hs[e]);
    }
}

__global__ void prefix_kernel(const int* __restrict__ cf, const int* __restrict__ cs,
                              int* __restrict__ bases, int* __restrict__ splits,
                              int* __restrict__ cnts) {
    int s = 0;
    for (int e = 0; e < E_NUM; ++e) {
        bases[e] = s;
        splits[e] = s + cf[e];
        cnts[e] = cf[e] + cs[e];
        s += cnts[e];
    }
}

// ---------------- assign: block-aggregated ranks (1024 global atomics) ------
__global__ __launch_bounds__(256) void assign_kernel(
    const int* __restrict__ topk_i, const float* __restrict__ topk_w,
    const int* __restrict__ bases, const int* __restrict__ splits,
    int* __restrict__ fills_f, int* __restrict__ fills_s,
    int* __restrict__ slot_tok, float* __restrict__ slot_w) {
    __shared__ int hf[E_NUM], hs[E_NUM], bf[E_NUM], bs[E_NUM];
    int tid = threadIdx.x;
    if (tid < E_NUM) { hf[tid] = 0; hs[tid] = 0; }
    __syncthreads();
    int t = blockIdx.x * 256 + tid;
    int e0 = topk_i[t * 2 + 0], e1 = topk_i[t * 2 + 1];
    int r0 = atomicAdd(&hf[e0], 1);
    int r1 = atomicAdd(&hs[e1], 1);
    __syncthreads();
    if (tid < E_NUM) {
        bf[tid] = hf[tid] ? atomicAdd(&fills_f[tid], hf[tid]) : 0;
    } else if (tid < 2 * E_NUM) {
        int e = tid - E_NUM;
        bs[e] = hs[e] ? atomicAdd(&fills_s[e], hs[e]) : 0;
    }
    __syncthreads();
    int s0 = bases[e0] + bf[e0] + r0;
    int s1 = splits[e1] + bs[e1] + r1;
    slot_tok[s0] = t; slot_w[s0] = topk_w[t * 2 + 0];
    slot_tok[s1] = t; slot_w[s1] = topk_w[t * 2 + 1];
}

// ---------------- converts --------------------------------------------------
// convert 4 experts' w1+w3 in one launch (group g: experts g*4..g*4+3)
__global__ __launch_bounds__(256) void cvt13g_kernel(const float* __restrict__ w1,
                                                     const float* __restrict__ w3,
                                                     uint16_t* __restrict__ w1be,
                                                     uint16_t* __restrict__ w3be, int g) {
    size_t i = (size_t)blockIdx.x * 256 + threadIdx.x;
    size_t off = (size_t)g * 4 * H_DIM * D_DIM / 4;
    ((ushort4*)w1be)[i] = f4_to_bf4(((const float4*)w1)[off + i]);
    ((ushort4*)w3be)[i] = f4_to_bf4(((const float4*)w3)[off + i]);
}
__global__ __launch_bounds__(256) void cvt2_kernel(const float* __restrict__ w2,
                                                   uint16_t* __restrict__ w2b) {
    size_t i = (size_t)blockIdx.x * 256 + threadIdx.x;
    ((ushort4*)w2b)[i] = f4_to_bf4(((const float4*)w2)[i]);
}

// ============================================================================
// BK=64 GEMM inner loop (r11, measured best: 1198us total). LDS rows 128B ->
// 3-bit XOR chunk swizzle; store via pre-swizzled global source, read chunk
// (kk*4+kq)^((rA>>1)&7). Conflict-zero measured.
// r13 change: DISPATCH-CONTIGUOUS grids. Old grids had expert in blockIdx.z
// (outermost) with m padded 4x -> alive blocks dispatched in per-expert
// clumps of ~256 (1/CU) separated by dead-block churn; measured occupancy
// 26.5% ~= 2 blocks/CU. New: (expert, n/d) in blockIdx.x (fastest), m in y ->
// alive region is a y-prefix across ALL experts; first ~Sum(alive) dispatched
// blocks are all real work. Kernel bodies unchanged from r11.
// ============================================================================

// ---------------- gemm1 (4 experts/launch): hidden = silu(Xe@w1^T)*(Xe@w3^T)
// 128(M) x 64(N, dual B1/B3), BK=64, single-buffer 32KB LDS.
// grid (172, 128): x -> ez = x/43 (n-sweep contiguous per expert), n_t = x%43.
__global__ __launch_bounds__(256) void gemm1_kernel(
    const uint16_t* __restrict__ Xb, const uint16_t* __restrict__ w1be,
    const uint16_t* __restrict__ w3be, const int* __restrict__ slot_tok,
    const int* __restrict__ cnts, const int* __restrict__ bases,
    uint16_t* __restrict__ hidden, int g) {
    int ez = blockIdx.x / 43;            // expert within group
    int n_t = blockIdx.x % 43;
    int e = g * 4 + ez;
    int cnt = cnts[e];
    int m0 = blockIdx.y * 128;
    if (m0 >= cnt) return;               // dead blocks: high y, dispatched last
    int n0 = n_t * 64;
    int base = bases[e];
    const uint16_t* w1p = w1be + (size_t)ez * H_DIM * D_DIM;
    const uint16_t* w3p = w3be + (size_t)ez * H_DIM * D_DIM;

    __shared__ __align__(16) uint16_t As[128 * 64];   // 16 KB
    __shared__ __align__(16) uint16_t B1s[64 * 64];   // 8 KB
    __shared__ __align__(16) uint16_t B3s[64 * 64];   // 8 KB

    int tid = threadIdx.x;
    int w = tid >> 6, lane = tid & 63;
    int rA = lane & 15, kq = lane >> 4;
    int r8 = lane >> 3;
    int srcc = (lane & 7) ^ ((w * 4 + (lane >> 4)) & 7);
    int xr = (rA >> 1) & 7;

    const uint16_t *pA0, *pA1, *pA2, *pA3, *pB1, *pB3;
    {
        int sr = w * 8 + r8;
        int t0 = slot_tok[base + min(m0 + 0 * 32 + sr, cnt - 1)];
        int t1 = slot_tok[base + min(m0 + 1 * 32 + sr, cnt - 1)];
        int t2 = slot_tok[base + min(m0 + 2 * 32 + sr, cnt - 1)];
        int t3 = slot_tok[base + min(m0 + 3 * 32 + sr, cnt - 1)];
        pA0 = Xb + (size_t)t0 * D_DIM + srcc * 8;
        pA1 = Xb + (size_t)t1 * D_DIM + srcc * 8;
        pA2 = Xb + (size_t)t2 * D_DIM + srcc * 8;
        pA3 = Xb + (size_t)t3 * D_DIM + srcc * 8;
        pB1 = w1p + (size_t)(n0 + sr) * D_DIM + srcc * 8;
        pB3 = w3p + (size_t)(n0 + sr) * D_DIM + srcc * 8;
    }
    uint16_t* lA = &As[(w * 8) * 64];
    uint16_t* lB1 = &B1s[(w * 8) * 64];
    uint16_t* lB3 = &B3s[(w * 8) * 64];

    f32x4_t acc1[2][4], acc3[2][4];
#pragma unroll
    for (int r = 0; r < 2; ++r)
#pragma unroll
        for (int n = 0; n < 4; ++n) {
            acc1[r][n] = (f32x4_t){0.f, 0.f, 0.f, 0.f};
            acc3[r][n] = (f32x4_t){0.f, 0.f, 0.f, 0.f};
        }

    for (int k0 = 0; k0 < D_DIM; k0 += 64) {  // 16 K-iters
        __syncthreads();
        gl_lds16(pA0, lA);
        gl_lds16(pA1, lA + 32 * 64);
        gl_lds16(pA2, lA + 64 * 64);
        gl_lds16(pA3, lA + 96 * 64);
        gl_lds16(pB1, lB1);
        gl_lds16(pB1 + 32 * D_DIM, lB1 + 32 * 64);
        gl_lds16(pB3, lB3);
        gl_lds16(pB3 + 32 * D_DIM, lB3 + 32 * 64);
        pA0 += 64; pA1 += 64; pA2 += 64; pA3 += 64; pB1 += 64; pB3 += 64;
        __syncthreads();

#pragma unroll
        for (int kk = 0; kk < 2; ++kk) {
            int ck = ((kk * 4 + kq) ^ xr) * 8;
            bf16x8_t a0 = *(const bf16x8_t*)&As[(w * 32 + rA) * 64 + ck];
            bf16x8_t a1 = *(const bf16x8_t*)&As[(w * 32 + 16 + rA) * 64 + ck];
#pragma unroll
            for (int n = 0; n < 4; ++n) {
                bf16x8_t b1 = *(const bf16x8_t*)&B1s[(n * 16 + rA) * 64 + ck];
                bf16x8_t b3 = *(const bf16x8_t*)&B3s[(n * 16 + rA) * 64 + ck];
                acc1[0][n] = __builtin_amdgcn_mfma_f32_16x16x32_bf16(a0, b1, acc1[0][n], 0, 0, 0);
                acc1[1][n] = __builtin_amdgcn_mfma_f32_16x16x32_bf16(a1, b1, acc1[1][n], 0, 0, 0);
                acc3[0][n] = __builtin_amdgcn_mfma_f32_16x16x32_bf16(a0, b3, acc3[0][n], 0, 0, 0);
                acc3[1][n] = __builtin_amdgcn_mfma_f32_16x16x32_bf16(a1, b3, acc3[1][n], 0, 0, 0);
            }
        }
    }

#pragma unroll
    for (int r = 0; r < 2; ++r)
#pragma unroll
        for (int n = 0; n < 4; ++n)
#pragma unroll
            for (int i = 0; i < 4; ++i) {
                int mrow = m0 + w * 32 + r * 16 + kq * 4 + i;
                if (mrow < cnt) {
                    float gv = acc1[r][n][i];
                    float s = gv / (1.0f + __expf(-gv));
                    float h = s * acc3[r][n][i];
                    hidden[(size_t)(base + mrow) * H_DIM + n0 + n * 16 + rA] = f2bf(h);
                }
            }
}

// ---------------- gemm2 (FUSED): out[tok] += w_slot * (hidden @ w2^T) -------
// 128(M) x 128(N=D), BK=64, 32KB LDS. atomicAdd into pre-zeroed out.
// grid (64, 128): x -> x_t = x&7 (d fastest), e = x>>3; m in y. The 8 d-tiles
// of one (e, m) A-panel are 8 consecutive bids -> 8 XCDs back-to-back (L3
// temporal sharing); alive blocks form a dispatch-contiguous y-prefix.
__global__ __launch_bounds__(256) void gemm2_kernel(
    const uint16_t* __restrict__ hidden, const uint16_t* __restrict__ w2b,
    const int* __restrict__ cnts, const int* __restrict__ bases,
    const int* __restrict__ slot_tok, const float* __restrict__ slot_w,
    float* __restrict__ out) {
    int x_t = blockIdx.x & 7;
    int e = blockIdx.x >> 3;
    int cnt = cnts[e];
    int m0 = blockIdx.y * 128;
    if (m0 >= cnt) return;               // dead blocks: high y, dispatched last
    int base = bases[e];
    int d0 = x_t * 128;

    __shared__ __align__(16) uint16_t As[128 * 64];  // 16 KB
    __shared__ __align__(16) uint16_t Bs[128 * 64];  // 16 KB

    int tid = threadIdx.x;
    int w = tid >> 6, lane = tid & 63;
    int rA = lane & 15, kq = lane >> 4;
    int r8 = lane >> 3;
    int srcc = (lane & 7) ^ ((w * 4 + (lane >> 4)) & 7);
    int xr = (rA >> 1) & 7;
    int mh = w & 1, nh = w >> 1;

    const uint16_t *pA0, *pA1, *pA2, *pA3, *pB;
    {
        int sr = w * 8 + r8;
        int s0 = base + min(m0 + 0 * 32 + sr, cnt - 1);
        int s1 = base + min(m0 + 1 * 32 + sr, cnt - 1);
        int s2 = base + min(m0 + 2 * 32 + sr, cnt - 1);
        int s3 = base + min(m0 + 3 * 32 + sr, cnt - 1);
        pA0 = hidden + (size_t)s0 * H_DIM + srcc * 8;
        pA1 = hidden + (size_t)s1 * H_DIM + srcc * 8;
        pA2 = hidden + (size_t)s2 * H_DIM + srcc * 8;
        pA3 = hidden + (size_t)s3 * H_DIM + srcc * 8;
        pB = w2b + (size_t)(e * D_DIM + d0 + sr) * H_DIM + srcc * 8;
    }
    uint16_t* lA = &As[(w * 8) * 64];
    uint16_t* lB = &Bs[(w * 8) * 64];

    f32x4_t acc[4][4];
#pragma unroll
    for (int mf = 0; mf < 4; ++mf)
#pragma unroll
        for (int nf = 0; nf < 4; ++nf) acc[mf][nf] = (f32x4_t){0.f, 0.f, 0.f, 0.f};

    for (int k0 = 0; k0 < H_DIM; k0 += 64) {  // 43 K-iters
        __syncthreads();
        gl_lds16(pA0, lA);
        gl_lds16(pA1, lA + 32 * 64);
        gl_lds16(pA2, lA + 64 * 64);
        gl_lds16(pA3, lA + 96 * 64);
        gl_lds16(pB, lB);
        gl_lds16(pB + 32 * H_DIM, lB + 32 * 64);
        gl_lds16(pB + 64 * H_DIM, lB + 64 * 64);
        gl_lds16(pB + 96 * H_DIM, lB + 96 * 64);
        pA0 += 64; pA1 += 64; pA2 += 64; pA3 += 64; pB += 64;
        __syncthreads();

#pragma unroll
        for (int kk = 0; kk < 2; ++kk) {
            int ck = ((kk * 4 + kq) ^ xr) * 8;
            bf16x8_t a[4], b[4];
#pragma unroll
            for (int mf = 0; mf < 4; ++mf)
                a[mf] = *(const bf16x8_t*)&As[(mh * 64 + mf * 16 + rA) * 64 + ck];
#pragma unroll
            for (int nf = 0; nf < 4; ++nf)
                b[nf] = *(const bf16x8_t*)&Bs[(nh * 64 + nf * 16 + rA) * 64 + ck];
#pragma unroll
            for (int mf = 0; mf < 4; ++mf)
#pragma unroll
                for (int nf = 0; nf < 4; ++nf)
                    acc[mf][nf] = __builtin_amdgcn_mfma_f32_16x16x32_bf16(a[mf], b[nf], acc[mf][nf], 0, 0, 0);
        }
    }

#pragma unroll
    for (int mf = 0; mf < 4; ++mf)
#pragma unroll
        for (int i = 0; i < 4; ++i) {
            int mr = m0 + mh * 64 + mf * 16 + kq * 4 + i;
            if (mr < cnt) {
                int slot = base + mr;
                float wgt = slot_w[slot];
                int tok = slot_tok[slot];
                float* yr = out + (size_t)tok * D_DIM + d0 + nh * 64;
#pragma unroll
                for (int nf = 0; nf < 4; ++nf)
                    atomicAdd(&yr[nf * 16 + rA], wgt * acc[mf][nf][i]);
            }
        }
}

// ---------------- launch ----------------------------------------------------
extern "C" void kernel_launch(void* const* d_in, const int* in_sizes, int n_in,
                              void* d_out, int out_size, void* d_ws, size_t ws_size,
                              hipStream_t stream) {
    const float* x  = (const float*)d_in[0];
    const float* gw = (const float*)d_in[1];
    const float* w1 = (const float*)d_in[2];
    const float* w2 = (const float*)d_in[3];
    const float* w3 = (const float*)d_in[4];
    float* out = (float*)d_out;
    char* ws = (char*)d_ws;

    int*   counts_f = (int*)(ws + 0);
    int*   counts_s = (int*)(ws + 256);
    int*   fills_f  = (int*)(ws + 512);
    int*   fills_s  = (int*)(ws + 768);
    int*   bases    = (int*)(ws + 1024);
    int*   splits   = (int*)(ws + 1280);
    int*   cnts     = (int*)(ws + 1536);
    int*   topk_i   = (int*)(ws + 4096);
    float* topk_w   = (float*)(ws + 4096 + 1 * 131072);
    int*   slot_tok = (int*)(ws + 4096 + 2 * 131072);
    float* slot_w   = (float*)(ws + 4096 + 3 * 131072);

    // r5 layout: hidden @4MiB (180.36MB); W region 45.09MB after hidden
    // (gemm1: w1be+w3be group; gemm2: w2b). Xb in d_out (dead until gemm2).
    const size_t HID_OFF = 4ull << 20;
    const size_t W_OFF   = HID_OFF + (size_t)NSLOT * H_DIM * 2;
    const size_t W1SZ    = (size_t)H_DIM * D_DIM * 2;
    uint16_t* hidden = (uint16_t*)(ws + HID_OFF);
    uint16_t* w1be   = (uint16_t*)(ws + W_OFF);
    uint16_t* w3be   = (uint16_t*)(ws + W_OFF + 4 * W1SZ);
    uint16_t* w2b    = (uint16_t*)(ws + W_OFF);
    uint16_t* Xb     = (uint16_t*)d_out;

    hipMemsetAsync(ws, 0, 1024, stream);

    router_kernel<<<T_TOK / 4, 256, 0, stream>>>(x, gw, topk_i, topk_w, Xb);
    count_kernel<<<T_TOK / 256, 256, 0, stream>>>(topk_i, counts_f, counts_s);
    prefix_kernel<<<1, 1, 0, stream>>>(counts_f, counts_s, bases, splits, cnts);
    assign_kernel<<<T_TOK / 256, 256, 0, stream>>>(topk_i, topk_w, bases, splits,
                                                   fills_f, fills_s, slot_tok, slot_w);

    for (int g = 0; g < 2; ++g) {
        cvt13g_kernel<<<H_DIM * 4, 256, 0, stream>>>(w1, w3, w1be, w3be, g);
        // x = (expert-in-group, n-tile): 4*43 = 172; y = m-tile (padded 128)
        gemm1_kernel<<<dim3(172, 128), 256, 0, stream>>>(
            Xb, w1be, w3be, slot_tok, cnts, bases, hidden, g);
    }

    // Xb dead; zero out for atomic accumulation in fused gemm2.
    hipMemsetAsync(out, 0, (size_t)T_TOK * D_DIM * sizeof(float), stream);
    cvt2_kernel<<<E_NUM * D_DIM * H_DIM / 1024, 256, 0, stream>>>(w2, w2b);
    // x = (expert, d-tile): 8*8 = 64; y = m-tile (padded 128)
    gemm2_kernel<<<dim3(64, 128), 256, 0, stream>>>(
        hidden, w2b, cnts, bases, slot_tok, slot_w, out);
}

// Round 14
// 1178.852 us; speedup vs baseline: 1.1174x; 1.0273x over previous
//
#include <hip/hip_runtime.h>
#include <hip/hip_bf16.h>
#include <stdint.h>

#define T_TOK 16384
#define D_DIM 1024
#define E_NUM 8
#define H_DIM 2752
#define NSLOT (T_TOK * 2)

typedef __bf16 bf16x8_t __attribute__((ext_vector_type(8)));
typedef float f32x4_t __attribute__((ext_vector_type(4)));

__device__ __forceinline__ uint16_t f2bf(float f) {
    union { float f; uint32_t u; } v; v.f = f;
    return (uint16_t)((v.u + 0x7FFFu + ((v.u >> 16) & 1u)) >> 16);  // RNE
}
__device__ __forceinline__ ushort4 f4_to_bf4(float4 v) {
    ushort4 r; r.x = f2bf(v.x); r.y = f2bf(v.y); r.z = f2bf(v.z); r.w = f2bf(v.w);
    return r;
}
// async global->LDS, 16B/lane; HW writes LDS at (wave-uniform base) + lane*16
__device__ __forceinline__ void gl_lds16(const uint16_t* g, uint16_t* l) {
    __builtin_amdgcn_global_load_lds((const __attribute__((address_space(1))) void*)g,
                                     (__attribute__((address_space(3))) void*)l,
                                     16, 0, 0);
}

// ---------------- router: fp64 logits, softmax top-2 + fused x->bf16 --------
// (r12-validated: x row is L1/L2-hot from the logit pass; removes the cvtx
//  launch + its 96MB of traffic. Logit math bit-identical to the verified r1.)
__global__ __launch_bounds__(256) void router_kernel(
    const float* __restrict__ x, const float* __restrict__ gw,
    int* __restrict__ topk_i, float* __restrict__ topk_w,
    uint16_t* __restrict__ Xb) {
    int tid = threadIdx.x;
    int t = blockIdx.x * 4 + (tid >> 6);
    int lane = tid & 63;
    const float* xr = x + (size_t)t * D_DIM;
    double acc[E_NUM];
#pragma unroll
    for (int e = 0; e < E_NUM; ++e) acc[e] = 0.0;
    for (int k = lane; k < D_DIM; k += 64) {
        double xv = (double)xr[k];
#pragma unroll
        for (int e = 0; e < E_NUM; ++e) acc[e] += xv * (double)gw[e * D_DIM + k];
    }
    // fused cvtx
    {
        const float4* x4 = (const float4*)xr;
        ushort4* b4 = (ushort4*)(Xb + (size_t)t * D_DIM);
#pragma unroll
        for (int j = 0; j < 4; ++j) b4[lane + j * 64] = f4_to_bf4(x4[lane + j * 64]);
    }
#pragma unroll
    for (int e = 0; e < E_NUM; ++e) {
        double v = acc[e];
        for (int off = 32; off > 0; off >>= 1) v += __shfl_down(v, off, 64);
        acc[e] = v;
    }
    if (lane == 0) {
        int i0 = 0; double m0 = acc[0];
#pragma unroll
        for (int e = 1; e < E_NUM; ++e) if (acc[e] > m0) { m0 = acc[e]; i0 = e; }
        int i1 = -1; double m1 = -1.0e300;
#pragma unroll
        for (int e = 0; e < E_NUM; ++e) if (e != i0 && acc[e] > m1) { m1 = acc[e]; i1 = e; }
        double e1 = exp(m1 - m0);
        double s = 1.0 + e1;
        topk_i[t * 2 + 0] = i0; topk_i[t * 2 + 1] = i1;
        topk_w[t * 2 + 0] = (float)(1.0 / s);
        topk_w[t * 2 + 1] = (float)(e1 / s);
    }
}

// ---------------- count: LDS-aggregated histogram (1024 global atomics) -----
__global__ __launch_bounds__(256) void count_kernel(
    const int* __restrict__ topk_i,
    int* __restrict__ counts_f, int* __restrict__ counts_s) {
    __shared__ int hf[E_NUM], hs[E_NUM];
    int tid = threadIdx.x;
    if (tid < E_NUM) { hf[tid] = 0; hs[tid] = 0; }
    __syncthreads();
    int t = blockIdx.x * 256 + tid;
    atomicAdd(&hf[topk_i[t * 2 + 0]], 1);
    atomicAdd(&hs[topk_i[t * 2 + 1]], 1);
    __syncthreads();
    if (tid < E_NUM) {
        if (hf[tid]) atomicAdd(&counts_f[tid], hf[tid]);
    } else if (tid < 2 * E_NUM) {
        int e = tid - E_NUM;
        if (hs[e]) atomicAdd(&counts_s[e], hs[e]);
    }
}

__global__ void prefix_kernel(const int* __restrict__ cf, const int* __restrict__ cs,
                              int* __restrict__ bases, int* __restrict__ splits,
                              int* __restrict__ cnts) {
    int s = 0;
    for (int e = 0; e < E_NUM; ++e) {
        bases[e] = s;
        splits[e] = s + cf[e];
        cnts[e] = cf[e] + cs[e];
        s += cnts[e];
    }
}

// ---------------- assign: block-aggregated ranks (1024 global atomics) ------
__global__ __launch_bounds__(256) void assign_kernel(
    const int* __restrict__ topk_i, const float* __restrict__ topk_w,
    const int* __restrict__ bases, const int* __restrict__ splits,
    int* __restrict__ fills_f, int* __restrict__ fills_s,
    int* __restrict__ slot_tok, float* __restrict__ slot_w) {
    __shared__ int hf[E_NUM], hs[E_NUM], bf[E_NUM], bs[E_NUM];
    int tid = threadIdx.x;
    if (tid < E_NUM) { hf[tid] = 0; hs[tid] = 0; }
    __syncthreads();
    int t = blockIdx.x * 256 + tid;
    int e0 = topk_i[t * 2 + 0], e1 = topk_i[t * 2 + 1];
    int r0 = atomicAdd(&hf[e0], 1);
    int r1 = atomicAdd(&hs[e1], 1);
    __syncthreads();
    if (tid < E_NUM) {
        bf[tid] = hf[tid] ? atomicAdd(&fills_f[tid], hf[tid]) : 0;
    } else if (tid < 2 * E_NUM) {
        int e = tid - E_NUM;
        bs[e] = hs[e] ? atomicAdd(&fills_s[e], hs[e]) : 0;
    }
    __syncthreads();
    int s0 = bases[e0] + bf[e0] + r0;
    int s1 = splits[e1] + bs[e1] + r1;
    slot_tok[s0] = t; slot_w[s0] = topk_w[t * 2 + 0];
    slot_tok[s1] = t; slot_w[s1] = topk_w[t * 2 + 1];
}

// ---------------- converts --------------------------------------------------
// convert 4 experts' w1+w3 in one launch (group g: experts g*4..g*4+3)
__global__ __launch_bounds__(256) void cvt13g_kernel(const float* __restrict__ w1,
                                                     const float* __restrict__ w3,
                                                     uint16_t* __restrict__ w1be,
                                                     uint16_t* __restrict__ w3be, int g) {
    size_t i = (size_t)blockIdx.x * 256 + threadIdx.x;
    size_t off = (size_t)g * 4 * H_DIM * D_DIM / 4;
    ((ushort4*)w1be)[i] = f4_to_bf4(((const float4*)w1)[off + i]);
    ((ushort4*)w3be)[i] = f4_to_bf4(((const float4*)w3)[off + i]);
}
__global__ __launch_bounds__(256) void cvt2_kernel(const float* __restrict__ w2,
                                                   uint16_t* __restrict__ w2b) {
    size_t i = (size_t)blockIdx.x * 256 + threadIdx.x;
    ((ushort4*)w2b)[i] = f4_to_bf4(((const float4*)w2)[i]);
}

// ============================================================================
// r11 BK=64 GEMM kernels (measured best: 1198us total) — restored verbatim.
// BK=64 halves barrier events per K vs BK=32 (the proven 2-phase lever).
// LDS rows 128B -> 3-bit XOR chunk swizzle; store via pre-swizzled global
// source (src_chunk = (lane&7) ^ ((w*4+lane>>4)&7), rows = 32i + 8w + r8);
// read chunk = (kk*4+kq) ^ ((rA>>1)&7). Conflict-zero measured.
// gemm2 keeps the r11 STRIPED decode (FETCH 280MB ~= 1.24x unique; r13's
// d-fastest order blew it to 915MB).
// ============================================================================

// ---------------- gemm1 (4 experts/launch): hidden = silu(Xe@w1^T)*(Xe@w3^T)
__global__ __launch_bounds__(256) void gemm1_kernel(
    const uint16_t* __restrict__ Xb, const uint16_t* __restrict__ w1be,
    const uint16_t* __restrict__ w3be, const int* __restrict__ slot_tok,
    const int* __restrict__ cnts, const int* __restrict__ bases,
    uint16_t* __restrict__ hidden, int g) {
    int ez = blockIdx.z;
    int e = g * 4 + ez;
    int cnt = cnts[e];
    int m0 = blockIdx.y * 128;
    if (m0 >= cnt) return;
    int n0 = blockIdx.x * 64;
    int base = bases[e];
    const uint16_t* w1p = w1be + (size_t)ez * H_DIM * D_DIM;
    const uint16_t* w3p = w3be + (size_t)ez * H_DIM * D_DIM;

    __shared__ __align__(16) uint16_t As[128 * 64];   // 16 KB
    __shared__ __align__(16) uint16_t B1s[64 * 64];   // 8 KB
    __shared__ __align__(16) uint16_t B3s[64 * 64];   // 8 KB

    int tid = threadIdx.x;
    int w = tid >> 6, lane = tid & 63;
    int rA = lane & 15, kq = lane >> 4;
    int r8 = lane >> 3;
    int srcc = (lane & 7) ^ ((w * 4 + (lane >> 4)) & 7);
    int xr = (rA >> 1) & 7;

    const uint16_t *pA0, *pA1, *pA2, *pA3, *pB1, *pB3;
    {
        int sr = w * 8 + r8;
        int t0 = slot_tok[base + min(m0 + 0 * 32 + sr, cnt - 1)];
        int t1 = slot_tok[base + min(m0 + 1 * 32 + sr, cnt - 1)];
        int t2 = slot_tok[base + min(m0 + 2 * 32 + sr, cnt - 1)];
        int t3 = slot_tok[base + min(m0 + 3 * 32 + sr, cnt - 1)];
        pA0 = Xb + (size_t)t0 * D_DIM + srcc * 8;
        pA1 = Xb + (size_t)t1 * D_DIM + srcc * 8;
        pA2 = Xb + (size_t)t2 * D_DIM + srcc * 8;
        pA3 = Xb + (size_t)t3 * D_DIM + srcc * 8;
        pB1 = w1p + (size_t)(n0 + sr) * D_DIM + srcc * 8;
        pB3 = w3p + (size_t)(n0 + sr) * D_DIM + srcc * 8;
    }
    uint16_t* lA = &As[(w * 8) * 64];
    uint16_t* lB1 = &B1s[(w * 8) * 64];
    uint16_t* lB3 = &B3s[(w * 8) * 64];

    f32x4_t acc1[2][4], acc3[2][4];
#pragma unroll
    for (int r = 0; r < 2; ++r)
#pragma unroll
        for (int n = 0; n < 4; ++n) {
            acc1[r][n] = (f32x4_t){0.f, 0.f, 0.f, 0.f};
            acc3[r][n] = (f32x4_t){0.f, 0.f, 0.f, 0.f};
        }

    for (int k0 = 0; k0 < D_DIM; k0 += 64) {  // 16 K-iters
        __syncthreads();
        gl_lds16(pA0, lA);
        gl_lds16(pA1, lA + 32 * 64);
        gl_lds16(pA2, lA + 64 * 64);
        gl_lds16(pA3, lA + 96 * 64);
        gl_lds16(pB1, lB1);
        gl_lds16(pB1 + 32 * D_DIM, lB1 + 32 * 64);
        gl_lds16(pB3, lB3);
        gl_lds16(pB3 + 32 * D_DIM, lB3 + 32 * 64);
        pA0 += 64; pA1 += 64; pA2 += 64; pA3 += 64; pB1 += 64; pB3 += 64;
        __syncthreads();

#pragma unroll
        for (int kk = 0; kk < 2; ++kk) {
            int ck = ((kk * 4 + kq) ^ xr) * 8;
            bf16x8_t a0 = *(const bf16x8_t*)&As[(w * 32 + rA) * 64 + ck];
            bf16x8_t a1 = *(const bf16x8_t*)&As[(w * 32 + 16 + rA) * 64 + ck];
#pragma unroll
            for (int n = 0; n < 4; ++n) {
                bf16x8_t b1 = *(const bf16x8_t*)&B1s[(n * 16 + rA) * 64 + ck];
                bf16x8_t b3 = *(const bf16x8_t*)&B3s[(n * 16 + rA) * 64 + ck];
                acc1[0][n] = __builtin_amdgcn_mfma_f32_16x16x32_bf16(a0, b1, acc1[0][n], 0, 0, 0);
                acc1[1][n] = __builtin_amdgcn_mfma_f32_16x16x32_bf16(a1, b1, acc1[1][n], 0, 0, 0);
                acc3[0][n] = __builtin_amdgcn_mfma_f32_16x16x32_bf16(a0, b3, acc3[0][n], 0, 0, 0);
                acc3[1][n] = __builtin_amdgcn_mfma_f32_16x16x32_bf16(a1, b3, acc3[1][n], 0, 0, 0);
            }
        }
    }

#pragma unroll
    for (int r = 0; r < 2; ++r)
#pragma unroll
        for (int n = 0; n < 4; ++n)
#pragma unroll
            for (int i = 0; i < 4; ++i) {
                int mrow = m0 + w * 32 + r * 16 + kq * 4 + i;
                if (mrow < cnt) {
                    float gv = acc1[r][n][i];
                    float s = gv / (1.0f + __expf(-gv));
                    float h = s * acc3[r][n][i];
                    hidden[(size_t)(base + mrow) * H_DIM + n0 + n * 16 + rA] = f2bf(h);
                }
            }
}

// ---------------- gemm2 (FUSED): out[tok] += w_slot * (hidden @ w2^T) -------
__global__ __launch_bounds__(256) void gemm2_kernel(
    const uint16_t* __restrict__ hidden, const uint16_t* __restrict__ w2b,
    const int* __restrict__ cnts, const int* __restrict__ bases,
    const int* __restrict__ slot_tok, const float* __restrict__ slot_w,
    float* __restrict__ out) {
    int e = blockIdx.z;
    int cnt = cnts[e];
    int lin = blockIdx.y * 8 + blockIdx.x;
    int c8 = lin & 7, j = lin >> 3;
    int m_t = (j >> 3) * 8 + c8;             // m_t % 8 == c8 (prefix-safe stripe)
    int x_t = j & 7;
    int m0 = m_t * 128;
    if (m0 >= cnt) return;
    int base = bases[e];
    int d0 = x_t * 128;

    __shared__ __align__(16) uint16_t As[128 * 64];  // 16 KB
    __shared__ __align__(16) uint16_t Bs[128 * 64];  // 16 KB

    int tid = threadIdx.x;
    int w = tid >> 6, lane = tid & 63;
    int rA = lane & 15, kq = lane >> 4;
    int r8 = lane >> 3;
    int srcc = (lane & 7) ^ ((w * 4 + (lane >> 4)) & 7);
    int xr = (rA >> 1) & 7;
    int mh = w & 1, nh = w >> 1;

    const uint16_t *pA0, *pA1, *pA2, *pA3, *pB;
    {
        int sr = w * 8 + r8;
        int s0 = base + min(m0 + 0 * 32 + sr, cnt - 1);
        int s1 = base + min(m0 + 1 * 32 + sr, cnt - 1);
        int s2 = base + min(m0 + 2 * 32 + sr, cnt - 1);
        int s3 = base + min(m0 + 3 * 32 + sr, cnt - 1);
        pA0 = hidden + (size_t)s0 * H_DIM + srcc * 8;
        pA1 = hidden + (size_t)s1 * H_DIM + srcc * 8;
        pA2 = hidden + (size_t)s2 * H_DIM + srcc * 8;
        pA3 = hidden + (size_t)s3 * H_DIM + srcc * 8;
        pB = w2b + (size_t)(e * D_DIM + d0 + sr) * H_DIM + srcc * 8;
    }
    uint16_t* lA = &As[(w * 8) * 64];
    uint16_t* lB = &Bs[(w * 8) * 64];

    f32x4_t acc[4][4];
#pragma unroll
    for (int mf = 0; mf < 4; ++mf)
#pragma unroll
        for (int nf = 0; nf < 4; ++nf) acc[mf][nf] = (f32x4_t){0.f, 0.f, 0.f, 0.f};

    for (int k0 = 0; k0 < H_DIM; k0 += 64) {  // 43 K-iters
        __syncthreads();
        gl_lds16(pA0, lA);
        gl_lds16(pA1, lA + 32 * 64);
        gl_lds16(pA2, lA + 64 * 64);
        gl_lds16(pA3, lA + 96 * 64);
        gl_lds16(pB, lB);
        gl_lds16(pB + 32 * H_DIM, lB + 32 * 64);
        gl_lds16(pB + 64 * H_DIM, lB + 64 * 64);
        gl_lds16(pB + 96 * H_DIM, lB + 96 * 64);
        pA0 += 64; pA1 += 64; pA2 += 64; pA3 += 64; pB += 64;
        __syncthreads();

#pragma unroll
        for (int kk = 0; kk < 2; ++kk) {
            int ck = ((kk * 4 + kq) ^ xr) * 8;
            bf16x8_t a[4], b[4];
#pragma unroll
            for (int mf = 0; mf < 4; ++mf)
                a[mf] = *(const bf16x8_t*)&As[(mh * 64 + mf * 16 + rA) * 64 + ck];
#pragma unroll
            for (int nf = 0; nf < 4; ++nf)
                b[nf] = *(const bf16x8_t*)&Bs[(nh * 64 + nf * 16 + rA) * 64 + ck];
#pragma unroll
            for (int mf = 0; mf < 4; ++mf)
#pragma unroll
                for (int nf = 0; nf < 4; ++nf)
                    acc[mf][nf] = __builtin_amdgcn_mfma_f32_16x16x32_bf16(a[mf], b[nf], acc[mf][nf], 0, 0, 0);
        }
    }

#pragma unroll
    for (int mf = 0; mf < 4; ++mf)
#pragma unroll
        for (int i = 0; i < 4; ++i) {
            int mr = m0 + mh * 64 + mf * 16 + kq * 4 + i;
            if (mr < cnt) {
                int slot = base + mr;
                float wgt = slot_w[slot];
                int tok = slot_tok[slot];
                float* yr = out + (size_t)tok * D_DIM + d0 + nh * 64;
#pragma unroll
                for (int nf = 0; nf < 4; ++nf)
                    atomicAdd(&yr[nf * 16 + rA], wgt * acc[mf][nf][i]);
            }
        }
}

// ---------------- launch ----------------------------------------------------
extern "C" void kernel_launch(void* const* d_in, const int* in_sizes, int n_in,
                              void* d_out, int out_size, void* d_ws, size_t ws_size,
                              hipStream_t stream) {
    const float* x  = (const float*)d_in[0];
    const float* gw = (const float*)d_in[1];
    const float* w1 = (const float*)d_in[2];
    const float* w2 = (const float*)d_in[3];
    const float* w3 = (const float*)d_in[4];
    float* out = (float*)d_out;
    char* ws = (char*)d_ws;

    int*   counts_f = (int*)(ws + 0);
    int*   counts_s = (int*)(ws + 256);
    int*   fills_f  = (int*)(ws + 512);
    int*   fills_s  = (int*)(ws + 768);
    int*   bases    = (int*)(ws + 1024);
    int*   splits   = (int*)(ws + 1280);
    int*   cnts     = (int*)(ws + 1536);
    int*   topk_i   = (int*)(ws + 4096);
    float* topk_w   = (float*)(ws + 4096 + 1 * 131072);
    int*   slot_tok = (int*)(ws + 4096 + 2 * 131072);
    float* slot_w   = (float*)(ws + 4096 + 3 * 131072);

    // r5/r11 layout: hidden @4MiB (180.36MB); W region 45.09MB after hidden
    // (gemm1: w1be+w3be group; gemm2: w2b). Xb in d_out (dead until gemm2;
    // memset(out) after gemm1 re-zeroes it for the atomic accumulation).
    const size_t HID_OFF = 4ull << 20;
    const size_t W_OFF   = HID_OFF + (size_t)NSLOT * H_DIM * 2;
    const size_t W1SZ    = (size_t)H_DIM * D_DIM * 2;
    uint16_t* hidden = (uint16_t*)(ws + HID_OFF);
    uint16_t* w1be   = (uint16_t*)(ws + W_OFF);
    uint16_t* w3be   = (uint16_t*)(ws + W_OFF + 4 * W1SZ);
    uint16_t* w2b    = (uint16_t*)(ws + W_OFF);
    uint16_t* Xb     = (uint16_t*)d_out;

    hipMemsetAsync(ws, 0, 1024, stream);

    router_kernel<<<T_TOK / 4, 256, 0, stream>>>(x, gw, topk_i, topk_w, Xb);
    count_kernel<<<T_TOK / 256, 256, 0, stream>>>(topk_i, counts_f, counts_s);
    prefix_kernel<<<1, 1, 0, stream>>>(counts_f, counts_s, bases, splits, cnts);
    assign_kernel<<<T_TOK / 256, 256, 0, stream>>>(topk_i, topk_w, bases, splits,
                                                   fills_f, fills_s, slot_tok, slot_w);

    for (int g = 0; g < 2; ++g) {
        cvt13g_kernel<<<H_DIM * 4, 256, 0, stream>>>(w1, w3, w1be, w3be, g);
        gemm1_kernel<<<dim3(H_DIM / 64, 128, 4), 256, 0, stream>>>(
            Xb, w1be, w3be, slot_tok, cnts, bases, hidden, g);
    }

    // Xb dead; zero out for atomic accumulation in fused gemm2.
    hipMemsetAsync(out, 0, (size_t)T_TOK * D_DIM * sizeof(float), stream);
    cvt2_kernel<<<E_NUM * D_DIM * H_DIM / 1024, 256, 0, stream>>>(w2, w2b);
    gemm2_kernel<<<dim3(8, 128, E_NUM), 256, 0, stream>>>(
        hidden, w2b, cnts, bases, slot_tok, slot_w, out);
}

// Round 15
// 1161.755 us; speedup vs baseline: 1.1339x; 1.0147x over previous
//
#include <hip/hip_runtime.h>
#include <hip/hip_bf16.h>
#include <stdint.h>

#define T_TOK 16384
#define D_DIM 1024
#define E_NUM 8
#define H_DIM 2752
#define NSLOT (T_TOK * 2)

typedef __bf16 bf16x8_t __attribute__((ext_vector_type(8)));
typedef float f32x4_t __attribute__((ext_vector_type(4)));
typedef float f32x16_t __attribute__((ext_vector_type(16)));

__device__ __forceinline__ uint16_t f2bf(float f) {
    union { float f; uint32_t u; } v; v.f = f;
    return (uint16_t)((v.u + 0x7FFFu + ((v.u >> 16) & 1u)) >> 16);  // RNE
}
__device__ __forceinline__ ushort4 f4_to_bf4(float4 v) {
    ushort4 r; r.x = f2bf(v.x); r.y = f2bf(v.y); r.z = f2bf(v.z); r.w = f2bf(v.w);
    return r;
}
// async global->LDS, 16B/lane; HW writes LDS at (wave-uniform base) + lane*16
__device__ __forceinline__ void gl_lds16(const uint16_t* g, uint16_t* l) {
    __builtin_amdgcn_global_load_lds((const __attribute__((address_space(1))) void*)g,
                                     (__attribute__((address_space(3))) void*)l,
                                     16, 0, 0);
}

// ---------------- router: fp64 logits, softmax top-2 + fused x->bf16 --------
__global__ __launch_bounds__(256) void router_kernel(
    const float* __restrict__ x, const float* __restrict__ gw,
    int* __restrict__ topk_i, float* __restrict__ topk_w,
    uint16_t* __restrict__ Xb) {
    int tid = threadIdx.x;
    int t = blockIdx.x * 4 + (tid >> 6);
    int lane = tid & 63;
    const float* xr = x + (size_t)t * D_DIM;
    double acc[E_NUM];
#pragma unroll
    for (int e = 0; e < E_NUM; ++e) acc[e] = 0.0;
    for (int k = lane; k < D_DIM; k += 64) {
        double xv = (double)xr[k];
#pragma unroll
        for (int e = 0; e < E_NUM; ++e) acc[e] += xv * (double)gw[e * D_DIM + k];
    }
    // fused cvtx
    {
        const float4* x4 = (const float4*)xr;
        ushort4* b4 = (ushort4*)(Xb + (size_t)t * D_DIM);
#pragma unroll
        for (int j = 0; j < 4; ++j) b4[lane + j * 64] = f4_to_bf4(x4[lane + j * 64]);
    }
#pragma unroll
    for (int e = 0; e < E_NUM; ++e) {
        double v = acc[e];
        for (int off = 32; off > 0; off >>= 1) v += __shfl_down(v, off, 64);
        acc[e] = v;
    }
    if (lane == 0) {
        int i0 = 0; double m0 = acc[0];
#pragma unroll
        for (int e = 1; e < E_NUM; ++e) if (acc[e] > m0) { m0 = acc[e]; i0 = e; }
        int i1 = -1; double m1 = -1.0e300;
#pragma unroll
        for (int e = 0; e < E_NUM; ++e) if (e != i0 && acc[e] > m1) { m1 = acc[e]; i1 = e; }
        double e1 = exp(m1 - m0);
        double s = 1.0 + e1;
        topk_i[t * 2 + 0] = i0; topk_i[t * 2 + 1] = i1;
        topk_w[t * 2 + 0] = (float)(1.0 / s);
        topk_w[t * 2 + 1] = (float)(e1 / s);
    }
}

// ---------------- count: LDS-aggregated histogram (1024 global atomics) -----
__global__ __launch_bounds__(256) void count_kernel(
    const int* __restrict__ topk_i,
    int* __restrict__ counts_f, int* __restrict__ counts_s) {
    __shared__ int hf[E_NUM], hs[E_NUM];
    int tid = threadIdx.x;
    if (tid < E_NUM) { hf[tid] = 0; hs[tid] = 0; }
    __syncthreads();
    int t = blockIdx.x * 256 + tid;
    atomicAdd(&hf[topk_i[t * 2 + 0]], 1);
    atomicAdd(&hs[topk_i[t * 2 + 1]], 1);
    __syncthreads();
    if (tid < E_NUM) {
        if (hf[tid]) atomicAdd(&counts_f[tid], hf[tid]);
    } else if (tid < 2 * E_NUM) {
        int e = tid - E_NUM;
        if (hs[e]) atomicAdd(&counts_s[e], hs[e]);
    }
}

__global__ void prefix_kernel(const int* __restrict__ cf, const int* __restrict__ cs,
                              int* __restrict__ bases, int* __restrict__ splits,
                              int* __restrict__ cnts) {
    int s = 0;
    for (int e = 0; e < E_NUM; ++e) {
        bases[e] = s;
        splits[e] = s + cf[e];
        cnts[e] = cf[e] + cs[e];
        s += cnts[e];
    }
}

// ---------------- assign: block-aggregated ranks (1024 global atomics) ------
__global__ __launch_bounds__(256) void assign_kernel(
    const int* __restrict__ topk_i, const float* __restrict__ topk_w,
    const int* __restrict__ bases, const int* __restrict__ splits,
    int* __restrict__ fills_f, int* __restrict__ fills_s,
    int* __restrict__ slot_tok, float* __restrict__ slot_w) {
    __shared__ int hf[E_NUM], hs[E_NUM], bf[E_NUM], bs[E_NUM];
    int tid = threadIdx.x;
    if (tid < E_NUM) { hf[tid] = 0; hs[tid] = 0; }
    __syncthreads();
    int t = blockIdx.x * 256 + tid;
    int e0 = topk_i[t * 2 + 0], e1 = topk_i[t * 2 + 1];
    int r0 = atomicAdd(&hf[e0], 1);
    int r1 = atomicAdd(&hs[e1], 1);
    __syncthreads();
    if (tid < E_NUM) {
        bf[tid] = hf[tid] ? atomicAdd(&fills_f[tid], hf[tid]) : 0;
    } else if (tid < 2 * E_NUM) {
        int e = tid - E_NUM;
        bs[e] = hs[e] ? atomicAdd(&fills_s[e], hs[e]) : 0;
    }
    __syncthreads();
    int s0 = bases[e0] + bf[e0] + r0;
    int s1 = splits[e1] + bs[e1] + r1;
    slot_tok[s0] = t; slot_w[s0] = topk_w[t * 2 + 0];
    slot_tok[s1] = t; slot_w[s1] = topk_w[t * 2 + 1];
}

// ---------------- converts --------------------------------------------------
__global__ __launch_bounds__(256) void cvt13g_kernel(const float* __restrict__ w1,
                                                     const float* __restrict__ w3,
                                                     uint16_t* __restrict__ w1be,
                                                     uint16_t* __restrict__ w3be, int g) {
    size_t i = (size_t)blockIdx.x * 256 + threadIdx.x;
    size_t off = (size_t)g * 4 * H_DIM * D_DIM / 4;
    ((ushort4*)w1be)[i] = f4_to_bf4(((const float4*)w1)[off + i]);
    ((ushort4*)w3be)[i] = f4_to_bf4(((const float4*)w3)[off + i]);
}
__global__ __launch_bounds__(256) void cvt2_kernel(const float* __restrict__ w2,
                                                   uint16_t* __restrict__ w2b) {
    size_t i = (size_t)blockIdx.x * 256 + threadIdx.x;
    ((ushort4*)w2b)[i] = f4_to_bf4(((const float4*)w2)[i]);
}

// ============================================================================
// r14 structure (best: 1179us), with the MFMA shape switched 16x16x32 ->
// 32x32x16: HALVES the matrix-pipe instruction count per K-tile (32->16) at
// a better per-op rate (2382 vs 2075 TF ubench), identical ds_read count and
// identical 64-f32 accumulator. C/D layout (m74/m101-verified):
//   col = lane&31, row = (reg&3) + 8*(reg>>2) + 4*(lane>>5), reg in [0,16).
// Swizzle algebra unchanged: all row offsets are multiples of 16, so the
// read xor reduces to ((lane&31)>>1)&7; store side (srcc) untouched.
// ============================================================================

// ---------------- gemm1 (4 experts/launch): hidden = silu(Xe@w1^T)*(Xe@w3^T)
// 128(M) x 64(N, dual B1/B3), BK=64, single-buffer 32KB LDS.
// Wave w: one 32-row m-frag (rows w*32..+31), 2 n-frags of 32 per matrix.
__global__ __launch_bounds__(256) void gemm1_kernel(
    const uint16_t* __restrict__ Xb, const uint16_t* __restrict__ w1be,
    const uint16_t* __restrict__ w3be, const int* __restrict__ slot_tok,
    const int* __restrict__ cnts, const int* __restrict__ bases,
    uint16_t* __restrict__ hidden, int g) {
    int ez = blockIdx.z;
    int e = g * 4 + ez;
    int cnt = cnts[e];
    int m0 = blockIdx.y * 128;
    if (m0 >= cnt) return;
    int n0 = blockIdx.x * 64;
    int base = bases[e];
    const uint16_t* w1p = w1be + (size_t)ez * H_DIM * D_DIM;
    const uint16_t* w3p = w3be + (size_t)ez * H_DIM * D_DIM;

    __shared__ __align__(16) uint16_t As[128 * 64];   // 16 KB
    __shared__ __align__(16) uint16_t B1s[64 * 64];   // 8 KB
    __shared__ __align__(16) uint16_t B3s[64 * 64];   // 8 KB

    int tid = threadIdx.x;
    int w = tid >> 6, lane = tid & 63;
    int l31 = lane & 31, khi = lane >> 5;
    int r8 = lane >> 3;
    int srcc = (lane & 7) ^ ((w * 4 + (lane >> 4)) & 7);
    int xr2 = (l31 >> 1) & 7;            // read-side xor (rows ≡ l31 mod 16)

    const uint16_t *pA0, *pA1, *pA2, *pA3, *pB1, *pB3;
    {
        int sr = w * 8 + r8;
        int t0 = slot_tok[base + min(m0 + 0 * 32 + sr, cnt - 1)];
        int t1 = slot_tok[base + min(m0 + 1 * 32 + sr, cnt - 1)];
        int t2 = slot_tok[base + min(m0 + 2 * 32 + sr, cnt - 1)];
        int t3 = slot_tok[base + min(m0 + 3 * 32 + sr, cnt - 1)];
        pA0 = Xb + (size_t)t0 * D_DIM + srcc * 8;
        pA1 = Xb + (size_t)t1 * D_DIM + srcc * 8;
        pA2 = Xb + (size_t)t2 * D_DIM + srcc * 8;
        pA3 = Xb + (size_t)t3 * D_DIM + srcc * 8;
        pB1 = w1p + (size_t)(n0 + sr) * D_DIM + srcc * 8;
        pB3 = w3p + (size_t)(n0 + sr) * D_DIM + srcc * 8;
    }
    uint16_t* lA = &As[(w * 8) * 64];
    uint16_t* lB1 = &B1s[(w * 8) * 64];
    uint16_t* lB3 = &B3s[(w * 8) * 64];

    f32x16_t acc1[2], acc3[2];
#pragma unroll
    for (int nf = 0; nf < 2; ++nf)
#pragma unroll
        for (int q = 0; q < 16; ++q) { acc1[nf][q] = 0.f; acc3[nf][q] = 0.f; }

    for (int k0 = 0; k0 < D_DIM; k0 += 64) {  // 16 K-iters
        __syncthreads();
        gl_lds16(pA0, lA);
        gl_lds16(pA1, lA + 32 * 64);
        gl_lds16(pA2, lA + 64 * 64);
        gl_lds16(pA3, lA + 96 * 64);
        gl_lds16(pB1, lB1);
        gl_lds16(pB1 + 32 * D_DIM, lB1 + 32 * 64);
        gl_lds16(pB3, lB3);
        gl_lds16(pB3 + 32 * D_DIM, lB3 + 32 * 64);
        pA0 += 64; pA1 += 64; pA2 += 64; pA3 += 64; pB1 += 64; pB3 += 64;
        __syncthreads();

#pragma unroll
        for (int ks = 0; ks < 4; ++ks) {       // 4 K-steps of 16
            int ca = ((ks * 2 + khi) ^ xr2) * 8;
            bf16x8_t a0  = *(const bf16x8_t*)&As[(w * 32 + l31) * 64 + ca];
            bf16x8_t b1l = *(const bf16x8_t*)&B1s[l31 * 64 + ca];
            bf16x8_t b1h = *(const bf16x8_t*)&B1s[(32 + l31) * 64 + ca];
            bf16x8_t b3l = *(const bf16x8_t*)&B3s[l31 * 64 + ca];
            bf16x8_t b3h = *(const bf16x8_t*)&B3s[(32 + l31) * 64 + ca];
            acc1[0] = __builtin_amdgcn_mfma_f32_32x32x16_bf16(a0, b1l, acc1[0], 0, 0, 0);
            acc1[1] = __builtin_amdgcn_mfma_f32_32x32x16_bf16(a0, b1h, acc1[1], 0, 0, 0);
            acc3[0] = __builtin_amdgcn_mfma_f32_32x32x16_bf16(a0, b3l, acc3[0], 0, 0, 0);
            acc3[1] = __builtin_amdgcn_mfma_f32_32x32x16_bf16(a0, b3h, acc3[1], 0, 0, 0);
        }
    }

    {
        int rbase = m0 + w * 32 + 4 * khi;
#pragma unroll
        for (int reg = 0; reg < 16; ++reg) {
            int mrow = rbase + (reg & 3) + 8 * (reg >> 2);
            if (mrow < cnt) {
                size_t ro = (size_t)(base + mrow) * H_DIM + n0 + l31;
#pragma unroll
                for (int nf = 0; nf < 2; ++nf) {
                    float gv = acc1[nf][reg];
                    float s = gv / (1.0f + __expf(-gv));
                    float h = s * acc3[nf][reg];
                    hidden[ro + nf * 32] = f2bf(h);
                }
            }
        }
    }
}

// ---------------- gemm2 (FUSED): out[tok] += w_slot * (hidden @ w2^T) -------
// 128(M) x 128(N=D), BK=64, 32KB LDS, striped decode. Wave: 64M x 64N =
// 2x2 frags of 32x32. atomicAdd into pre-zeroed out (commutative).
__global__ __launch_bounds__(256) void gemm2_kernel(
    const uint16_t* __restrict__ hidden, const uint16_t* __restrict__ w2b,
    const int* __restrict__ cnts, const int* __restrict__ bases,
    const int* __restrict__ slot_tok, const float* __restrict__ slot_w,
    float* __restrict__ out) {
    int e = blockIdx.z;
    int cnt = cnts[e];
    int lin = blockIdx.y * 8 + blockIdx.x;
    int c8 = lin & 7, j = lin >> 3;
    int m_t = (j >> 3) * 8 + c8;             // m_t % 8 == c8 (prefix-safe stripe)
    int x_t = j & 7;
    int m0 = m_t * 128;
    if (m0 >= cnt) return;
    int base = bases[e];
    int d0 = x_t * 128;

    __shared__ __align__(16) uint16_t As[128 * 64];  // 16 KB
    __shared__ __align__(16) uint16_t Bs[128 * 64];  // 16 KB

    int tid = threadIdx.x;
    int w = tid >> 6, lane = tid & 63;
    int l31 = lane & 31, khi = lane >> 5;
    int r8 = lane >> 3;
    int srcc = (lane & 7) ^ ((w * 4 + (lane >> 4)) & 7);
    int xr2 = (l31 >> 1) & 7;
    int mh = w & 1, nh = w >> 1;

    const uint16_t *pA0, *pA1, *pA2, *pA3, *pB;
    {
        int sr = w * 8 + r8;
        int s0 = base + min(m0 + 0 * 32 + sr, cnt - 1);
        int s1 = base + min(m0 + 1 * 32 + sr, cnt - 1);
        int s2 = base + min(m0 + 2 * 32 + sr, cnt - 1);
        int s3 = base + min(m0 + 3 * 32 + sr, cnt - 1);
        pA0 = hidden + (size_t)s0 * H_DIM + srcc * 8;
        pA1 = hidden + (size_t)s1 * H_DIM + srcc * 8;
        pA2 = hidden + (size_t)s2 * H_DIM + srcc * 8;
        pA3 = hidden + (size_t)s3 * H_DIM + srcc * 8;
        pB = w2b + (size_t)(e * D_DIM + d0 + sr) * H_DIM + srcc * 8;
    }
    uint16_t* lA = &As[(w * 8) * 64];
    uint16_t* lB = &Bs[(w * 8) * 64];

    f32x16_t acc[2][2];
#pragma unroll
    for (int mf = 0; mf < 2; ++mf)
#pragma unroll
        for (int nf = 0; nf < 2; ++nf)
#pragma unroll
            for (int q = 0; q < 16; ++q) acc[mf][nf][q] = 0.f;

    for (int k0 = 0; k0 < H_DIM; k0 += 64) {  // 43 K-iters
        __syncthreads();
        gl_lds16(pA0, lA);
        gl_lds16(pA1, lA + 32 * 64);
        gl_lds16(pA2, lA + 64 * 64);
        gl_lds16(pA3, lA + 96 * 64);
        gl_lds16(pB, lB);
        gl_lds16(pB + 32 * H_DIM, lB + 32 * 64);
        gl_lds16(pB + 64 * H_DIM, lB + 64 * 64);
        gl_lds16(pB + 96 * H_DIM, lB + 96 * 64);
        pA0 += 64; pA1 += 64; pA2 += 64; pA3 += 64; pB += 64;
        __syncthreads();

#pragma unroll
        for (int ks = 0; ks < 4; ++ks) {       // 4 K-steps of 16
            int ca = ((ks * 2 + khi) ^ xr2) * 8;
            bf16x8_t a0 = *(const bf16x8_t*)&As[(mh * 64 + l31) * 64 + ca];
            bf16x8_t a1 = *(const bf16x8_t*)&As[(mh * 64 + 32 + l31) * 64 + ca];
            bf16x8_t b0 = *(const bf16x8_t*)&Bs[(nh * 64 + l31) * 64 + ca];
            bf16x8_t b1 = *(const bf16x8_t*)&Bs[(nh * 64 + 32 + l31) * 64 + ca];
            acc[0][0] = __builtin_amdgcn_mfma_f32_32x32x16_bf16(a0, b0, acc[0][0], 0, 0, 0);
            acc[0][1] = __builtin_amdgcn_mfma_f32_32x32x16_bf16(a0, b1, acc[0][1], 0, 0, 0);
            acc[1][0] = __builtin_amdgcn_mfma_f32_32x32x16_bf16(a1, b0, acc[1][0], 0, 0, 0);
            acc[1][1] = __builtin_amdgcn_mfma_f32_32x32x16_bf16(a1, b1, acc[1][1], 0, 0, 0);
        }
    }

#pragma unroll
    for (int mf = 0; mf < 2; ++mf) {
        int rbase = m0 + mh * 64 + mf * 32 + 4 * khi;
#pragma unroll
        for (int reg = 0; reg < 16; ++reg) {
            int mr = rbase + (reg & 3) + 8 * (reg >> 2);
            if (mr < cnt) {
                int slot = base + mr;
                float wgt = slot_w[slot];
                int tok = slot_tok[slot];
                float* yr = out + (size_t)tok * D_DIM + d0 + nh * 64 + l31;
#pragma unroll
                for (int nf = 0; nf < 2; ++nf)
                    atomicAdd(&yr[nf * 32], wgt * acc[mf][nf][reg]);
            }
        }
    }
}

// ---------------- launch ----------------------------------------------------
extern "C" void kernel_launch(void* const* d_in, const int* in_sizes, int n_in,
                              void* d_out, int out_size, void* d_ws, size_t ws_size,
                              hipStream_t stream) {
    const float* x  = (const float*)d_in[0];
    const float* gw = (const float*)d_in[1];
    const float* w1 = (const float*)d_in[2];
    const float* w2 = (const float*)d_in[3];
    const float* w3 = (const float*)d_in[4];
    float* out = (float*)d_out;
    char* ws = (char*)d_ws;

    int*   counts_f = (int*)(ws + 0);
    int*   counts_s = (int*)(ws + 256);
    int*   fills_f  = (int*)(ws + 512);
    int*   fills_s  = (int*)(ws + 768);
    int*   bases    = (int*)(ws + 1024);
    int*   splits   = (int*)(ws + 1280);
    int*   cnts     = (int*)(ws + 1536);
    int*   topk_i   = (int*)(ws + 4096);
    float* topk_w   = (float*)(ws + 4096 + 1 * 131072);
    int*   slot_tok = (int*)(ws + 4096 + 2 * 131072);
    float* slot_w   = (float*)(ws + 4096 + 3 * 131072);

    // r5/r11 layout: hidden @4MiB (180.36MB); W region 45.09MB after hidden
    // (gemm1: w1be+w3be group; gemm2: w2b). Xb in d_out (dead until gemm2;
    // memset(out) after gemm1 re-zeroes it for the atomic accumulation).
    const size_t HID_OFF = 4ull << 20;
    const size_t W_OFF   = HID_OFF + (size_t)NSLOT * H_DIM * 2;
    const size_t W1SZ    = (size_t)H_DIM * D_DIM * 2;
    uint16_t* hidden = (uint16_t*)(ws + HID_OFF);
    uint16_t* w1be   = (uint16_t*)(ws + W_OFF);
    uint16_t* w3be   = (uint16_t*)(ws + W_OFF + 4 * W1SZ);
    uint16_t* w2b    = (uint16_t*)(ws + W_OFF);
    uint16_t* Xb     = (uint16_t*)d_out;

    hipMemsetAsync(ws, 0, 1024, stream);

    router_kernel<<<T_TOK / 4, 256, 0, stream>>>(x, gw, topk_i, topk_w, Xb);
    count_kernel<<<T_TOK / 256, 256, 0, stream>>>(topk_i, counts_f, counts_s);
    prefix_kernel<<<1, 1, 0, stream>>>(counts_f, counts_s, bases, splits, cnts);
    assign_kernel<<<T_TOK / 256, 256, 0, stream>>>(topk_i, topk_w, bases, splits,
                                                   fills_f, fills_s, slot_tok, slot_w);

    for (int g = 0; g < 2; ++g) {
        cvt13g_kernel<<<H_DIM * 4, 256, 0, stream>>>(w1, w3, w1be, w3be, g);
        gemm1_kernel<<<dim3(H_DIM / 64, 128, 4), 256, 0, stream>>>(
            Xb, w1be, w3be, slot_tok, cnts, bases, hidden, g);
    }

    // Xb dead; zero out for atomic accumulation in fused gemm2.
    hipMemsetAsync(out, 0, (size_t)T_TOK * D_DIM * sizeof(float), stream);
    cvt2_kernel<<<E_NUM * D_DIM * H_DIM / 1024, 256, 0, stream>>>(w2, w2b);
    gemm2_kernel<<<dim3(8, 128, E_NUM), 256, 0, stream>>>(
        hidden, w2b, cnts, bases, slot_tok, slot_w, out);
}

// Round 16
// 1160.395 us; speedup vs baseline: 1.1352x; 1.0012x over previous
//
#include <hip/hip_runtime.h>
#include <hip/hip_bf16.h>
#include <stdint.h>

#define T_TOK 16384
#define D_DIM 1024
#define E_NUM 8
#define H_DIM 2752
#define NSLOT (T_TOK * 2)

typedef __bf16 bf16x8_t __attribute__((ext_vector_type(8)));
typedef float f32x4_t __attribute__((ext_vector_type(4)));
typedef float f32x16_t __attribute__((ext_vector_type(16)));

__device__ __forceinline__ uint16_t f2bf(float f) {
    union { float f; uint32_t u; } v; v.f = f;
    return (uint16_t)((v.u + 0x7FFFu + ((v.u >> 16) & 1u)) >> 16);  // RNE
}
__device__ __forceinline__ ushort4 f4_to_bf4(float4 v) {
    ushort4 r; r.x = f2bf(v.x); r.y = f2bf(v.y); r.z = f2bf(v.z); r.w = f2bf(v.w);
    return r;
}
// async global->LDS, 16B/lane; HW writes LDS at (wave-uniform base) + lane*16
__device__ __forceinline__ void gl_lds16(const uint16_t* g, uint16_t* l) {
    __builtin_amdgcn_global_load_lds((const __attribute__((address_space(1))) void*)g,
                                     (__attribute__((address_space(3))) void*)l,
                                     16, 0, 0);
}

// ---------------- router: fp64 logits, softmax top-2 + fused x->bf16 --------
__global__ __launch_bounds__(256) void router_kernel(
    const float* __restrict__ x, const float* __restrict__ gw,
    int* __restrict__ topk_i, float* __restrict__ topk_w,
    uint16_t* __restrict__ Xb) {
    int tid = threadIdx.x;
    int t = blockIdx.x * 4 + (tid >> 6);
    int lane = tid & 63;
    const float* xr = x + (size_t)t * D_DIM;
    double acc[E_NUM];
#pragma unroll
    for (int e = 0; e < E_NUM; ++e) acc[e] = 0.0;
    for (int k = lane; k < D_DIM; k += 64) {
        double xv = (double)xr[k];
#pragma unroll
        for (int e = 0; e < E_NUM; ++e) acc[e] += xv * (double)gw[e * D_DIM + k];
    }
    // fused cvtx
    {
        const float4* x4 = (const float4*)xr;
        ushort4* b4 = (ushort4*)(Xb + (size_t)t * D_DIM);
#pragma unroll
        for (int j = 0; j < 4; ++j) b4[lane + j * 64] = f4_to_bf4(x4[lane + j * 64]);
    }
#pragma unroll
    for (int e = 0; e < E_NUM; ++e) {
        double v = acc[e];
        for (int off = 32; off > 0; off >>= 1) v += __shfl_down(v, off, 64);
        acc[e] = v;
    }
    if (lane == 0) {
        int i0 = 0; double m0 = acc[0];
#pragma unroll
        for (int e = 1; e < E_NUM; ++e) if (acc[e] > m0) { m0 = acc[e]; i0 = e; }
        int i1 = -1; double m1 = -1.0e300;
#pragma unroll
        for (int e = 0; e < E_NUM; ++e) if (e != i0 && acc[e] > m1) { m1 = acc[e]; i1 = e; }
        double e1 = exp(m1 - m0);
        double s = 1.0 + e1;
        topk_i[t * 2 + 0] = i0; topk_i[t * 2 + 1] = i1;
        topk_w[t * 2 + 0] = (float)(1.0 / s);
        topk_w[t * 2 + 1] = (float)(e1 / s);
    }
}

// ---------------- count: LDS-aggregated histogram (1024 global atomics) -----
__global__ __launch_bounds__(256) void count_kernel(
    const int* __restrict__ topk_i,
    int* __restrict__ counts_f, int* __restrict__ counts_s) {
    __shared__ int hf[E_NUM], hs[E_NUM];
    int tid = threadIdx.x;
    if (tid < E_NUM) { hf[tid] = 0; hs[tid] = 0; }
    __syncthreads();
    int t = blockIdx.x * 256 + tid;
    atomicAdd(&hf[topk_i[t * 2 + 0]], 1);
    atomicAdd(&hs[topk_i[t * 2 + 1]], 1);
    __syncthreads();
    if (tid < E_NUM) {
        if (hf[tid]) atomicAdd(&counts_f[tid], hf[tid]);
    } else if (tid < 2 * E_NUM) {
        int e = tid - E_NUM;
        if (hs[e]) atomicAdd(&counts_s[e], hs[e]);
    }
}

__global__ void prefix_kernel(const int* __restrict__ cf, const int* __restrict__ cs,
                              int* __restrict__ bases, int* __restrict__ splits,
                              int* __restrict__ cnts) {
    int s = 0;
    for (int e = 0; e < E_NUM; ++e) {
        bases[e] = s;
        splits[e] = s + cf[e];
        cnts[e] = cf[e] + cs[e];
        s += cnts[e];
    }
}

// ---------------- assign: block-aggregated ranks (1024 global atomics) ------
__global__ __launch_bounds__(256) void assign_kernel(
    const int* __restrict__ topk_i, const float* __restrict__ topk_w,
    const int* __restrict__ bases, const int* __restrict__ splits,
    int* __restrict__ fills_f, int* __restrict__ fills_s,
    int* __restrict__ slot_tok, float* __restrict__ slot_w) {
    __shared__ int hf[E_NUM], hs[E_NUM], bf[E_NUM], bs[E_NUM];
    int tid = threadIdx.x;
    if (tid < E_NUM) { hf[tid] = 0; hs[tid] = 0; }
    __syncthreads();
    int t = blockIdx.x * 256 + tid;
    int e0 = topk_i[t * 2 + 0], e1 = topk_i[t * 2 + 1];
    int r0 = atomicAdd(&hf[e0], 1);
    int r1 = atomicAdd(&hs[e1], 1);
    __syncthreads();
    if (tid < E_NUM) {
        bf[tid] = hf[tid] ? atomicAdd(&fills_f[tid], hf[tid]) : 0;
    } else if (tid < 2 * E_NUM) {
        int e = tid - E_NUM;
        bs[e] = hs[e] ? atomicAdd(&fills_s[e], hs[e]) : 0;
    }
    __syncthreads();
    int s0 = bases[e0] + bf[e0] + r0;
    int s1 = splits[e1] + bs[e1] + r1;
    slot_tok[s0] = t; slot_w[s0] = topk_w[t * 2 + 0];
    slot_tok[s1] = t; slot_w[s1] = topk_w[t * 2 + 1];
}

// ---------------- converts --------------------------------------------------
__global__ __launch_bounds__(256) void cvt13g_kernel(const float* __restrict__ w1,
                                                     const float* __restrict__ w3,
                                                     uint16_t* __restrict__ w1be,
                                                     uint16_t* __restrict__ w3be, int g) {
    size_t i = (size_t)blockIdx.x * 256 + threadIdx.x;
    size_t off = (size_t)g * 4 * H_DIM * D_DIM / 4;
    ((ushort4*)w1be)[i] = f4_to_bf4(((const float4*)w1)[off + i]);
    ((ushort4*)w3be)[i] = f4_to_bf4(((const float4*)w3)[off + i]);
}
__global__ __launch_bounds__(256) void cvt2_kernel(const float* __restrict__ w2,
                                                   uint16_t* __restrict__ w2b) {
    size_t i = (size_t)blockIdx.x * 256 + threadIdx.x;
    ((ushort4*)w2b)[i] = f4_to_bf4(((const float4*)w2)[i]);
}

// ============================================================================
// r15 structure (best: 1162us): BK=64, 32x32x16 MFMA (halved inst count,
// VALUBusy 8.6% -> headroom for pipeline addressing), 3-bit XOR swizzle.
// C/D layout: col = lane&31, row = (reg&3) + 8*(reg>>2) + 4*(lane>>5).
// r16 change (gemm2 only): 2-buffer LDS + counted vmcnt(8) pipeline.
// Per iter: issue next tile's 8 gl_lds into the idle buffer -> vmcnt(8)
// (waits ONLY the previous batch, issued one full iteration earlier) ->
// raw s_barrier -> compute current buffer -> barrier. The drain that the
// 2-phase structure paid every iter now has a full iteration of cover.
// LDS 64KB caps residency at 2 blocks/CU ~= measured effective 2.2 -> no
// residency tax (the r3/r6 confounds - dbuf residency loss and VALU
// saturation - are both absent here).
// ============================================================================

// ---------------- gemm1 (4 experts/launch): hidden = silu(Xe@w1^T)*(Xe@w3^T)
// (unchanged from r15 — above the 2-phase ceiling already; attribution clean)
__global__ __launch_bounds__(256) void gemm1_kernel(
    const uint16_t* __restrict__ Xb, const uint16_t* __restrict__ w1be,
    const uint16_t* __restrict__ w3be, const int* __restrict__ slot_tok,
    const int* __restrict__ cnts, const int* __restrict__ bases,
    uint16_t* __restrict__ hidden, int g) {
    int ez = blockIdx.z;
    int e = g * 4 + ez;
    int cnt = cnts[e];
    int m0 = blockIdx.y * 128;
    if (m0 >= cnt) return;
    int n0 = blockIdx.x * 64;
    int base = bases[e];
    const uint16_t* w1p = w1be + (size_t)ez * H_DIM * D_DIM;
    const uint16_t* w3p = w3be + (size_t)ez * H_DIM * D_DIM;

    __shared__ __align__(16) uint16_t As[128 * 64];   // 16 KB
    __shared__ __align__(16) uint16_t B1s[64 * 64];   // 8 KB
    __shared__ __align__(16) uint16_t B3s[64 * 64];   // 8 KB

    int tid = threadIdx.x;
    int w = tid >> 6, lane = tid & 63;
    int l31 = lane & 31, khi = lane >> 5;
    int r8 = lane >> 3;
    int srcc = (lane & 7) ^ ((w * 4 + (lane >> 4)) & 7);
    int xr2 = (l31 >> 1) & 7;            // read-side xor (rows ≡ l31 mod 16)

    const uint16_t *pA0, *pA1, *pA2, *pA3, *pB1, *pB3;
    {
        int sr = w * 8 + r8;
        int t0 = slot_tok[base + min(m0 + 0 * 32 + sr, cnt - 1)];
        int t1 = slot_tok[base + min(m0 + 1 * 32 + sr, cnt - 1)];
        int t2 = slot_tok[base + min(m0 + 2 * 32 + sr, cnt - 1)];
        int t3 = slot_tok[base + min(m0 + 3 * 32 + sr, cnt - 1)];
        pA0 = Xb + (size_t)t0 * D_DIM + srcc * 8;
        pA1 = Xb + (size_t)t1 * D_DIM + srcc * 8;
        pA2 = Xb + (size_t)t2 * D_DIM + srcc * 8;
        pA3 = Xb + (size_t)t3 * D_DIM + srcc * 8;
        pB1 = w1p + (size_t)(n0 + sr) * D_DIM + srcc * 8;
        pB3 = w3p + (size_t)(n0 + sr) * D_DIM + srcc * 8;
    }
    uint16_t* lA = &As[(w * 8) * 64];
    uint16_t* lB1 = &B1s[(w * 8) * 64];
    uint16_t* lB3 = &B3s[(w * 8) * 64];

    f32x16_t acc1[2], acc3[2];
#pragma unroll
    for (int nf = 0; nf < 2; ++nf)
#pragma unroll
        for (int q = 0; q < 16; ++q) { acc1[nf][q] = 0.f; acc3[nf][q] = 0.f; }

    for (int k0 = 0; k0 < D_DIM; k0 += 64) {  // 16 K-iters
        __syncthreads();
        gl_lds16(pA0, lA);
        gl_lds16(pA1, lA + 32 * 64);
        gl_lds16(pA2, lA + 64 * 64);
        gl_lds16(pA3, lA + 96 * 64);
        gl_lds16(pB1, lB1);
        gl_lds16(pB1 + 32 * D_DIM, lB1 + 32 * 64);
        gl_lds16(pB3, lB3);
        gl_lds16(pB3 + 32 * D_DIM, lB3 + 32 * 64);
        pA0 += 64; pA1 += 64; pA2 += 64; pA3 += 64; pB1 += 64; pB3 += 64;
        __syncthreads();

#pragma unroll
        for (int ks = 0; ks < 4; ++ks) {       // 4 K-steps of 16
            int ca = ((ks * 2 + khi) ^ xr2) * 8;
            bf16x8_t a0  = *(const bf16x8_t*)&As[(w * 32 + l31) * 64 + ca];
            bf16x8_t b1l = *(const bf16x8_t*)&B1s[l31 * 64 + ca];
            bf16x8_t b1h = *(const bf16x8_t*)&B1s[(32 + l31) * 64 + ca];
            bf16x8_t b3l = *(const bf16x8_t*)&B3s[l31 * 64 + ca];
            bf16x8_t b3h = *(const bf16x8_t*)&B3s[(32 + l31) * 64 + ca];
            acc1[0] = __builtin_amdgcn_mfma_f32_32x32x16_bf16(a0, b1l, acc1[0], 0, 0, 0);
            acc1[1] = __builtin_amdgcn_mfma_f32_32x32x16_bf16(a0, b1h, acc1[1], 0, 0, 0);
            acc3[0] = __builtin_amdgcn_mfma_f32_32x32x16_bf16(a0, b3l, acc3[0], 0, 0, 0);
            acc3[1] = __builtin_amdgcn_mfma_f32_32x32x16_bf16(a0, b3h, acc3[1], 0, 0, 0);
        }
    }

    {
        int rbase = m0 + w * 32 + 4 * khi;
#pragma unroll
        for (int reg = 0; reg < 16; ++reg) {
            int mrow = rbase + (reg & 3) + 8 * (reg >> 2);
            if (mrow < cnt) {
                size_t ro = (size_t)(base + mrow) * H_DIM + n0 + l31;
#pragma unroll
                for (int nf = 0; nf < 2; ++nf) {
                    float gv = acc1[nf][reg];
                    float s = gv / (1.0f + __expf(-gv));
                    float h = s * acc3[nf][reg];
                    hidden[ro + nf * 32] = f2bf(h);
                }
            }
        }
    }
}

// ---------------- gemm2 (FUSED): out[tok] += w_slot * (hidden @ w2^T) -------
// 128(M) x 128(N=D), BK=64, 2-BUFFER 64KB LDS + counted vmcnt(8) pipeline,
// striped decode. Wave: 2x2 frags of 32x32. atomicAdd into pre-zeroed out.
__global__ __launch_bounds__(256) void gemm2_kernel(
    const uint16_t* __restrict__ hidden, const uint16_t* __restrict__ w2b,
    const int* __restrict__ cnts, const int* __restrict__ bases,
    const int* __restrict__ slot_tok, const float* __restrict__ slot_w,
    float* __restrict__ out) {
    int e = blockIdx.z;
    int cnt = cnts[e];
    int lin = blockIdx.y * 8 + blockIdx.x;
    int c8 = lin & 7, j = lin >> 3;
    int m_t = (j >> 3) * 8 + c8;             // m_t % 8 == c8 (prefix-safe stripe)
    int x_t = j & 7;
    int m0 = m_t * 128;
    if (m0 >= cnt) return;
    int base = bases[e];
    int d0 = x_t * 128;

    __shared__ __align__(16) uint16_t As[2][128 * 64];  // 32 KB
    __shared__ __align__(16) uint16_t Bs[2][128 * 64];  // 32 KB

    int tid = threadIdx.x;
    int w = tid >> 6, lane = tid & 63;
    int l31 = lane & 31, khi = lane >> 5;
    int r8 = lane >> 3;
    int srcc = (lane & 7) ^ ((w * 4 + (lane >> 4)) & 7);
    int xr2 = (l31 >> 1) & 7;
    int mh = w & 1, nh = w >> 1;

    const uint16_t *pA0, *pA1, *pA2, *pA3, *pB;
    {
        int sr = w * 8 + r8;
        int s0 = base + min(m0 + 0 * 32 + sr, cnt - 1);
        int s1 = base + min(m0 + 1 * 32 + sr, cnt - 1);
        int s2 = base + min(m0 + 2 * 32 + sr, cnt - 1);
        int s3 = base + min(m0 + 3 * 32 + sr, cnt - 1);
        pA0 = hidden + (size_t)s0 * H_DIM + srcc * 8;
        pA1 = hidden + (size_t)s1 * H_DIM + srcc * 8;
        pA2 = hidden + (size_t)s2 * H_DIM + srcc * 8;
        pA3 = hidden + (size_t)s3 * H_DIM + srcc * 8;
        pB = w2b + (size_t)(e * D_DIM + d0 + sr) * H_DIM + srcc * 8;
    }

#define G2_STAGE(bi) do {                                          \
        uint16_t* lA = &As[bi][(w * 8) * 64];                      \
        uint16_t* lB = &Bs[bi][(w * 8) * 64];                      \
        gl_lds16(pA0, lA);                                         \
        gl_lds16(pA1, lA + 32 * 64);                               \
        gl_lds16(pA2, lA + 64 * 64);                               \
        gl_lds16(pA3, lA + 96 * 64);                               \
        gl_lds16(pB, lB);                                          \
        gl_lds16(pB + 32 * H_DIM, lB + 32 * 64);                   \
        gl_lds16(pB + 64 * H_DIM, lB + 64 * 64);                   \
        gl_lds16(pB + 96 * H_DIM, lB + 96 * 64);                   \
        pA0 += 64; pA1 += 64; pA2 += 64; pA3 += 64; pB += 64; } while (0)

    f32x16_t acc[2][2];
#pragma unroll
    for (int mf = 0; mf < 2; ++mf)
#pragma unroll
        for (int nf = 0; nf < 2; ++nf)
#pragma unroll
            for (int q = 0; q < 16; ++q) acc[mf][nf][q] = 0.f;

    G2_STAGE(0);                             // prologue: tile 0 -> buf 0
    for (int t = 0; t < 43; ++t) {           // 43 K-iters (H=2752, BK=64)
        int cur = t & 1;
        if (t < 42) {
            G2_STAGE(cur ^ 1);               // issue next tile into idle buf
            asm volatile("s_waitcnt vmcnt(8)" ::: "memory");  // prev batch done
        } else {
            asm volatile("s_waitcnt vmcnt(0)" ::: "memory");
        }
        __builtin_amdgcn_s_barrier();        // buf[cur] visible to all waves

        const uint16_t* A = As[cur];
        const uint16_t* B = Bs[cur];
#pragma unroll
        for (int ks = 0; ks < 4; ++ks) {     // 4 K-steps of 16
            int ca = ((ks * 2 + khi) ^ xr2) * 8;
            bf16x8_t a0 = *(const bf16x8_t*)&A[(mh * 64 + l31) * 64 + ca];
            bf16x8_t a1 = *(const bf16x8_t*)&A[(mh * 64 + 32 + l31) * 64 + ca];
            bf16x8_t b0 = *(const bf16x8_t*)&B[(nh * 64 + l31) * 64 + ca];
            bf16x8_t b1 = *(const bf16x8_t*)&B[(nh * 64 + 32 + l31) * 64 + ca];
            acc[0][0] = __builtin_amdgcn_mfma_f32_32x32x16_bf16(a0, b0, acc[0][0], 0, 0, 0);
            acc[0][1] = __builtin_amdgcn_mfma_f32_32x32x16_bf16(a0, b1, acc[0][1], 0, 0, 0);
            acc[1][0] = __builtin_amdgcn_mfma_f32_32x32x16_bf16(a1, b0, acc[1][0], 0, 0, 0);
            acc[1][1] = __builtin_amdgcn_mfma_f32_32x32x16_bf16(a1, b1, acc[1][1], 0, 0, 0);
        }
        __builtin_amdgcn_s_barrier();        // reads done before buf reuse
    }
#undef G2_STAGE

#pragma unroll
    for (int mf = 0; mf < 2; ++mf) {
        int rbase = m0 + mh * 64 + mf * 32 + 4 * khi;
#pragma unroll
        for (int reg = 0; reg < 16; ++reg) {
            int mr = rbase + (reg & 3) + 8 * (reg >> 2);
            if (mr < cnt) {
                int slot = base + mr;
                float wgt = slot_w[slot];
                int tok = slot_tok[slot];
                float* yr = out + (size_t)tok * D_DIM + d0 + nh * 64 + l31;
#pragma unroll
                for (int nf = 0; nf < 2; ++nf)
                    atomicAdd(&yr[nf * 32], wgt * acc[mf][nf][reg]);
            }
        }
    }
}

// ---------------- launch ----------------------------------------------------
extern "C" void kernel_launch(void* const* d_in, const int* in_sizes, int n_in,
                              void* d_out, int out_size, void* d_ws, size_t ws_size,
                              hipStream_t stream) {
    const float* x  = (const float*)d_in[0];
    const float* gw = (const float*)d_in[1];
    const float* w1 = (const float*)d_in[2];
    const float* w2 = (const float*)d_in[3];
    const float* w3 = (const float*)d_in[4];
    float* out = (float*)d_out;
    char* ws = (char*)d_ws;

    int*   counts_f = (int*)(ws + 0);
    int*   counts_s = (int*)(ws + 256);
    int*   fills_f  = (int*)(ws + 512);
    int*   fills_s  = (int*)(ws + 768);
    int*   bases    = (int*)(ws + 1024);
    int*   splits   = (int*)(ws + 1280);
    int*   cnts     = (int*)(ws + 1536);
    int*   topk_i   = (int*)(ws + 4096);
    float* topk_w   = (float*)(ws + 4096 + 1 * 131072);
    int*   slot_tok = (int*)(ws + 4096 + 2 * 131072);
    float* slot_w   = (float*)(ws + 4096 + 3 * 131072);

    // r5/r11 layout: hidden @4MiB (180.36MB); W region 45.09MB after hidden
    // (gemm1: w1be+w3be group; gemm2: w2b). Xb in d_out (dead until gemm2;
    // memset(out) after gemm1 re-zeroes it for the atomic accumulation).
    const size_t HID_OFF = 4ull << 20;
    const size_t W_OFF   = HID_OFF + (size_t)NSLOT * H_DIM * 2;
    const size_t W1SZ    = (size_t)H_DIM * D_DIM * 2;
    uint16_t* hidden = (uint16_t*)(ws + HID_OFF);
    uint16_t* w1be   = (uint16_t*)(ws + W_OFF);
    uint16_t* w3be   = (uint16_t*)(ws + W_OFF + 4 * W1SZ);
    uint16_t* w2b    = (uint16_t*)(ws + W_OFF);
    uint16_t* Xb     = (uint16_t*)d_out;

    hipMemsetAsync(ws, 0, 1024, stream);

    router_kernel<<<T_TOK / 4, 256, 0, stream>>>(x, gw, topk_i, topk_w, Xb);
    count_kernel<<<T_TOK / 256, 256, 0, stream>>>(topk_i, counts_f, counts_s);
    prefix_kernel<<<1, 1, 0, stream>>>(counts_f, counts_s, bases, splits, cnts);
    assign_kernel<<<T_TOK / 256, 256, 0, stream>>>(topk_i, topk_w, bases, splits,
                                                   fills_f, fills_s, slot_tok, slot_w);

    for (int g = 0; g < 2; ++g) {
        cvt13g_kernel<<<H_DIM * 4, 256, 0, stream>>>(w1, w3, w1be, w3be, g);
        gemm1_kernel<<<dim3(H_DIM / 64, 128, 4), 256, 0, stream>>>(
            Xb, w1be, w3be, slot_tok, cnts, bases, hidden, g);
    }

    // Xb dead; zero out for atomic accumulation in fused gemm2.
    hipMemsetAsync(out, 0, (size_t)T_TOK * D_DIM * sizeof(float), stream);
    cvt2_kernel<<<E_NUM * D_DIM * H_DIM / 1024, 256, 0, stream>>>(w2, w2b);
    gemm2_kernel<<<dim3(8, 128, E_NUM), 256, 0, stream>>>(
        hidden, w2b, cnts, bases, slot_tok, slot_w, out);
}